// Round 4
// baseline (363.727 us; speedup 1.0000x reference)
//
#include <hip/hip_runtime.h>
#include <math.h>

// GAT 2-layer pipeline. CSR-by-dst built per launch via LDS-staged counting
// sort into FIXED-CAPACITY buckets (16384 slots/bucket). Aggregation:
// atomic-free per-node online softmax, bf16 features (absmax ~4e-3 << 1.1e-2
// threshold). Layer-1 GEMM on MFMA (bf16): h^T = W^T . x^T.
// Sizes fixed by reference: F_IN=256, HEADS=8, HID=8 -> C1=64; layer2 1x1.
//
// R4: merge R2's execution shape with R3's traffic shape. R3 proved src-slice
// phasing cuts agg1 FETCH 224->119MB (slices L2-resident) but its 8-lane
// serial-edge layout was latency-bound (97us, 1.26TB/s). R4 keeps the sliced
// csr + pcnt and restores the 16-lane/node, 4-edge-slot register-state kernel
// (R2: 42% VALUBusy @3.1TB/s), phases as an inner loop. Co-residency for
// phase lockstep: persistent 2048-block grid (8 blocks/CU via
// launch_bounds(256,8), VGPR<=64) grid-striding 16-node tiles -> all blocks
// sweep slices in rough lockstep -> working set ~2 slices (~3.2MB) < 4MB L2.
#define FIN 256
#define C1  64
#define NH  8
#define HID 8
#define MAXBUK 512        // buckets of 256 nodes; N=100000 -> 391 buckets
#define CAPLOG 14         // fixed bucket capacity 16384 edges
#define SC_CHUNK 8192     // edges per k_bscatter block (512 thr, EPT 16)
#define EPT (SC_CHUNK / 512)
#define NSLICE 8          // src slices for agg1 phasing
#define SLDIV 12500u      // slice = src / SLDIV (N=100000 -> 8 even slices)
#define AGG_GRID 2048     // persistent blocks: 8/CU x 256 CU, all co-resident

typedef unsigned short ushort_t;
typedef unsigned int uint_t;
typedef __attribute__((ext_vector_type(8))) short short8;   // 8 x bf16 MFMA frag
typedef __attribute__((ext_vector_type(4))) float f32x4;    // MFMA acc

__device__ __forceinline__ ushort_t f2bf(float f) {   // round-to-nearest-even
    uint_t u = __float_as_uint(f);
    u += 0x7fffu + ((u >> 16) & 1u);
    return (ushort_t)(u >> 16);
}
__device__ __forceinline__ uint_t packbf2(float lo, float hi) {
    return (uint_t)f2bf(lo) | ((uint_t)f2bf(hi) << 16);
}
__device__ __forceinline__ float bf_lo(uint_t w) { return __uint_as_float(w << 16); }
__device__ __forceinline__ float bf_hi(uint_t w) { return __uint_as_float(w & 0xffff0000u); }

// ---------------- prep: zero bkt_cnt + transpose W -> global bf16 Wt[64][256] ----------------
__global__ void k_prep(const float* __restrict__ W, ushort_t* __restrict__ Wtg,
                       int* __restrict__ bkt_cnt) {
    int tid = blockIdx.x * 256 + threadIdx.x;
    if (tid < MAXBUK) bkt_cnt[tid] = 0;
    int c = tid >> 8;        // 0..63
    int k = tid & 255;       // 0..255
    Wtg[c * 256 + k] = f2bf(W[k * C1 + c]);
}

// ---------------- bucket scatter: packed edges into fixed-capacity buckets ----------------
__global__ __launch_bounds__(512) void k_bscatter(const int* __restrict__ ei, int E, int N,
                                                  int NBUK, int* __restrict__ bkt_cnt,
                                                  uint_t* __restrict__ ebuf) {
    __shared__ int hist[MAXBUK];
    __shared__ int loff[MAXBUK];     // local exclusive offsets; reused as rank cursor
    __shared__ int delta[MAXBUK];    // global_base - local_offset
    __shared__ int ssum[MAXBUK];
    __shared__ uint_t vals[SC_CHUNK];     // 32 KB
    __shared__ ushort_t buks[SC_CHUNK];   // 16 KB

    const int t = threadIdx.x;
    hist[t] = 0;
    __syncthreads();

    const int Etot = E + N;
    const int base0 = blockIdx.x * SC_CHUNK;
    const int lim = min(base0 + SC_CHUNK, Etot);
    const int cnt = lim - base0;

    uint_t myval[EPT];
    int myb[EPT];
#pragma unroll
    for (int i = 0; i < EPT; ++i) {
        int e = base0 + t + i * 512;
        if (e < lim) {
            int s, d;
            if (e < E) { s = ei[e]; d = ei[E + e]; } else { s = e - E; d = s; }
            myval[i] = ((uint_t)s << 8) | (uint_t)(d & 255);
            myb[i] = d >> 8;
            atomicAdd(&hist[myb[i]], 1);
        } else myb[i] = -1;
    }
    __syncthreads();

    // exclusive scan of hist[0..511] with 512 threads
    int v = hist[t];
    ssum[t] = v;
    __syncthreads();
    for (int o = 1; o < 512; o <<= 1) {
        int add = (t >= o) ? ssum[t - o] : 0;
        __syncthreads();
        ssum[t] += add;
        __syncthreads();
    }
    loff[t] = ssum[t] - v;   // exclusive
    __syncthreads();

    // global reservation: one atomic per touched bucket; base = b<<CAPLOG
    if (t < NBUK) {
        int c = hist[t];
        if (c) delta[t] = (t << CAPLOG) + atomicAdd(&bkt_cnt[t], c) - loff[t];
    }
    __syncthreads();

    // rank into staging (loff doubles as cursor; delta already captured)
#pragma unroll
    for (int i = 0; i < EPT; ++i) {
        if (myb[i] >= 0) {
            int pos = atomicAdd(&loff[myb[i]], 1);
            vals[pos] = myval[i];
            buks[pos] = (ushort_t)myb[i];
        }
    }
    __syncthreads();

    // linear write-out: consecutive i -> consecutive gaddr within each run
    for (int i = t; i < cnt; i += 512)
        ebuf[delta[buks[i]] + i] = vals[i];
}

// ---------------- per-bucket: degrees, offsets, per-slice counts, csr scatter ----------------
// One block (512 threads) per bucket. Histogram is (local_node, src_slice) =
// 2048 counters -> csr ordered by (node, slice); pcnt[n] = 8 x u8 slice
// counts (max per-slice deg ~ Binom(70,1/8) << 255).
__global__ __launch_bounds__(512) void k_bucket_csr(const uint_t* __restrict__ ebuf,
                                                    const int* __restrict__ bkt_cnt, int N,
                                                    int* __restrict__ deg, int* __restrict__ off,
                                                    int* __restrict__ csr,
                                                    uint2* __restrict__ pcnt) {
    __shared__ int hist[256 * NSLICE];   // 8 KB; counts, then cursors
    __shared__ int ssum[512];
    int b = blockIdx.x;
    int t = threadIdx.x;
    int beg = b << CAPLOG;
    int end = beg + bkt_cnt[b];
    for (int i = t; i < 256 * NSLICE; i += 512) hist[i] = 0;
    __syncthreads();
    for (int j = beg + t; j < end; j += 512) {
        uint_t v = ebuf[j];
        int key = ((v & 255u) << 3) | ((v >> 8) / SLDIV);
        atomicAdd(&hist[key], 1);
    }
    __syncthreads();
    // pcnt + deg (pure reads of hist)
    if (t < 256) {
        int node = (b << 8) + t;
        int c[8]; int s = 0;
#pragma unroll
        for (int i = 0; i < 8; ++i) { c[i] = hist[(t << 3) | i]; s += c[i]; }
        if (node < N) {
            deg[node] = s;
            uint2 pc;
            pc.x = (uint_t)c[0] | ((uint_t)c[1] << 8) | ((uint_t)c[2] << 16) | ((uint_t)c[3] << 24);
            pc.y = (uint_t)c[4] | ((uint_t)c[5] << 8) | ((uint_t)c[6] << 16) | ((uint_t)c[7] << 24);
            pcnt[node] = pc;
        }
    }
    // scan of 2048: thread t owns hist[4t..4t+3]
    int c0 = hist[4 * t], c1 = hist[4 * t + 1], c2 = hist[4 * t + 2], c3 = hist[4 * t + 3];
    int s4 = c0 + c1 + c2 + c3;
    __syncthreads();              // all reads of counts complete before overwrite
    ssum[t] = s4;
    __syncthreads();
    for (int o = 1; o < 512; o <<= 1) {
        int add = (t >= o) ? ssum[t - o] : 0;
        __syncthreads();
        ssum[t] += add;
        __syncthreads();
    }
    int base = beg + ssum[t] - s4;   // global exclusive prefix (cursor init)
    hist[4 * t]     = base;
    hist[4 * t + 1] = base + c0;
    hist[4 * t + 2] = base + c0 + c1;
    hist[4 * t + 3] = base + c0 + c1 + c2;
    __syncthreads();
    if (t < 256) {
        int node = (b << 8) + t;
        if (node < N) off[node] = hist[t << 3];
    }
    __syncthreads();
    for (int j = beg + t; j < end; j += 512) {
        uint_t v = ebuf[j];
        int key = ((v & 255u) << 3) | ((v >> 8) / SLDIV);
        int pos = atomicAdd(&hist[key], 1);
        csr[pos] = (int)(v >> 8);
    }
}

// ---------------- layer1 GEMM via MFMA + attention terms (bf16 outputs) ----------------
// h^T = W^T . x^T per mfma_f32_16x16x32_bf16 tile so D cols = nodes.
// NO LDS: A-fragments read from global bf16 Wt[64][256] (32KB, L1/L2
// resident). 64 nodes/block -> grid 1563, no staging prologue.
__global__ __launch_bounds__(256) void k_gemm1(
    const float* __restrict__ x, const ushort_t* __restrict__ Wtg,
    const float* __restrict__ att_s, const float* __restrict__ att_d,
    ushort_t* __restrict__ h1b, ushort_t* __restrict__ as1b, float* __restrict__ ad1, int N)
{
    const int t = threadIdx.x;
    const int wv = t >> 6, l = t & 63;
    const int l15 = l & 15, q = l >> 4;
    const int node = blockIdx.x * 64 + wv * 16 + l15;
    const bool ok = node < N;
    const float* xr = x + (size_t)(ok ? node : N - 1) * FIN;

    f32x4 acc[4];   // [ct] : output channels ct*16 + q*4 + 0..3, col = node
#pragma unroll
    for (int ct = 0; ct < 4; ++ct) acc[ct] = (f32x4){0.f, 0.f, 0.f, 0.f};

    for (int kk = 0; kk < 8; ++kk) {
        const int kof = kk * 32 + q * 8;
        short8 af[4];
#pragma unroll
        for (int ct = 0; ct < 4; ++ct)
            af[ct] = *reinterpret_cast<const short8*>(&Wtg[(ct * 16 + l15) * 256 + kof]);
        const float4* xp = reinterpret_cast<const float4*>(xr + kof);
        float4 v0 = xp[0], v1 = xp[1];
        union { short8 s; uint_t u[4]; } bu;
        bu.u[0] = packbf2(v0.x, v0.y);
        bu.u[1] = packbf2(v0.z, v0.w);
        bu.u[2] = packbf2(v1.x, v1.y);
        bu.u[3] = packbf2(v1.z, v1.w);
#pragma unroll
        for (int ct = 0; ct < 4; ++ct)
            acc[ct] = __builtin_amdgcn_mfma_f32_16x16x32_bf16(af[ct], bu.s, acc[ct], 0, 0, 0);
    }

    float4 ats[4], atd4[4];
#pragma unroll
    for (int ct = 0; ct < 4; ++ct) {
        ats[ct]  = *reinterpret_cast<const float4*>(&att_s[ct * 16 + q * 4]);
        atd4[ct] = *reinterpret_cast<const float4*>(&att_d[ct * 16 + q * 4]);
    }
    const int hb = q >> 1;

    float asp[8], adp[8];
#pragma unroll
    for (int h = 0; h < 8; ++h) { asp[h] = 0.f; adp[h] = 0.f; }
#pragma unroll
    for (int ct = 0; ct < 4; ++ct) {
        f32x4 a = acc[ct];
        if (ok) {
            uint2 hv;
            hv.x = packbf2(a[0], a[1]);
            hv.y = packbf2(a[2], a[3]);
            *reinterpret_cast<uint2*>(&h1b[(size_t)node * C1 + ct * 16 + q * 4]) = hv;
        }
        int h = ct * 2 + hb;
        asp[h] = a[0] * ats[ct].x + a[1] * ats[ct].y + a[2] * ats[ct].z + a[3] * ats[ct].w;
        adp[h] = a[0] * atd4[ct].x + a[1] * atd4[ct].y + a[2] * atd4[ct].z + a[3] * atd4[ct].w;
    }
#pragma unroll
    for (int o = 16; o <= 32; o <<= 1) {
#pragma unroll
        for (int h = 0; h < 8; ++h) {
            asp[h] += __shfl_xor(asp[h], o, 64);
            adp[h] += __shfl_xor(adp[h], o, 64);
        }
    }
    if (q == 0 && ok) {
        uint4 aw;
        aw.x = packbf2(asp[0], asp[1]);
        aw.y = packbf2(asp[2], asp[3]);
        aw.z = packbf2(asp[4], asp[5]);
        aw.w = packbf2(asp[6], asp[7]);
        *reinterpret_cast<uint4*>(&as1b[(size_t)node * NH]) = aw;
        *reinterpret_cast<float4*>(&ad1[(size_t)node * NH]) =
            make_float4(adp[0], adp[1], adp[2], adp[3]);
        *reinterpret_cast<float4*>(&ad1[(size_t)node * NH + 4]) =
            make_float4(adp[4], adp[5], adp[6], adp[7]);
    }
}

// ---------------- fused layer1 aggregation + bias/ELU + W2 projection ----------------
// R2 shape + R3 traffic: 4 nodes/wave, 16 lanes/node (slot = sub>>2 gives 4
// edges in flight; hp = sub&3 gives 32B of the h1 record per lane), state in
// registers; inner loop over the 8 src-slices of the reordered csr.
// Persistent co-resident grid (2048 blocks, 8/CU) sweeps 16-node tiles so all
// waves walk slices in near-lockstep -> gather working set ~2 slices < 4MB L2.
__global__ __launch_bounds__(256, 8) void k_agg1(
    const int* __restrict__ csr, const int* __restrict__ off, const uint2* __restrict__ pcnt,
    const ushort_t* __restrict__ as1b, const float* __restrict__ ad1,
    const ushort_t* __restrict__ h1b,
    const float* __restrict__ b1, const float* __restrict__ W2,
    float* __restrict__ h2, int N)
{
    const int sub  = threadIdx.x & 15;
    const int hp   = sub & 3;
    const int slot = sub >> 2;
    const int rowb = threadIdx.x >> 4;   // 0..15: node row within block

    // epilogue constants (loop-invariant)
    const float4* bp = reinterpret_cast<const float4*>(&b1[hp * 16]);
    const float4* wp = reinterpret_cast<const float4*>(&W2[hp * 16]);
    float bb[16], ww[16];
#pragma unroll
    for (int i = 0; i < 4; ++i) {
        float4 b4 = bp[i], w4 = wp[i];
        bb[4 * i] = b4.x; bb[4 * i + 1] = b4.y; bb[4 * i + 2] = b4.z; bb[4 * i + 3] = b4.w;
        ww[4 * i] = w4.x; ww[4 * i + 1] = w4.y; ww[4 * i + 2] = w4.z; ww[4 * i + 3] = w4.w;
    }

    for (int tile = blockIdx.x; tile * 16 < N; tile += gridDim.x) {
        const int n = tile * 16 + rowb;
        const bool okn = n < N;
        const int nn = okn ? n : N - 1;

        int cur = off[nn];
        const uint2 pc = pcnt[nn];
        const float adv0 = ad1[(size_t)nn * NH + 2 * hp];
        const float adv1 = ad1[(size_t)nn * NH + 2 * hp + 1];
        float den0 = 0.f, den1 = 0.f;
        float acc[16];
#pragma unroll
        for (int k = 0; k < 16; ++k) acc[k] = 0.f;

        for (int p = 0; p < NSLICE; ++p) {
            const uint_t w = (p < 4) ? pc.x : pc.y;
            const int cnt = (w >> ((p & 3) * 8)) & 255u;
            for (int i = slot; i < cnt; i += 4) {
                int s = csr[cur + i];
                uint_t a2 = *reinterpret_cast<const uint_t*>(&as1b[(size_t)s * NH + 2 * hp]);
                float t0 = bf_lo(a2) + adv0;
                float t1 = bf_hi(a2) + adv1;
                t0 = fmaxf(t0, 0.2f * t0);
                t1 = fmaxf(t1, 0.2f * t1);
                float ex0 = __expf(t0);
                float ex1 = __expf(t1);
                den0 += ex0; den1 += ex1;
                const uint4* hbp = reinterpret_cast<const uint4*>(&h1b[(size_t)s * C1 + hp * 16]);
                uint4 u0 = hbp[0], u1 = hbp[1];
                acc[0]  = fmaf(ex0, bf_lo(u0.x), acc[0]);
                acc[1]  = fmaf(ex0, bf_hi(u0.x), acc[1]);
                acc[2]  = fmaf(ex0, bf_lo(u0.y), acc[2]);
                acc[3]  = fmaf(ex0, bf_hi(u0.y), acc[3]);
                acc[4]  = fmaf(ex0, bf_lo(u0.z), acc[4]);
                acc[5]  = fmaf(ex0, bf_hi(u0.z), acc[5]);
                acc[6]  = fmaf(ex0, bf_lo(u0.w), acc[6]);
                acc[7]  = fmaf(ex0, bf_hi(u0.w), acc[7]);
                acc[8]  = fmaf(ex1, bf_lo(u1.x), acc[8]);
                acc[9]  = fmaf(ex1, bf_hi(u1.x), acc[9]);
                acc[10] = fmaf(ex1, bf_lo(u1.y), acc[10]);
                acc[11] = fmaf(ex1, bf_hi(u1.y), acc[11]);
                acc[12] = fmaf(ex1, bf_lo(u1.z), acc[12]);
                acc[13] = fmaf(ex1, bf_hi(u1.z), acc[13]);
                acc[14] = fmaf(ex1, bf_lo(u1.w), acc[14]);
                acc[15] = fmaf(ex1, bf_hi(u1.w), acc[15]);
            }
            cur += cnt;
        }

#pragma unroll
        for (int o = 4; o <= 8; o <<= 1) {
            den0 += __shfl_xor(den0, o, 64);
            den1 += __shfl_xor(den1, o, 64);
#pragma unroll
            for (int k = 0; k < 16; ++k) acc[k] += __shfl_xor(acc[k], o, 64);
        }

        float inv0 = 1.f / (den0 + 1e-16f);
        float inv1 = 1.f / (den1 + 1e-16f);
        float p2 = 0.f;
#pragma unroll
        for (int k = 0; k < 16; ++k) {
            float inv = (k < 8) ? inv0 : inv1;
            float v = acc[k] * inv + bb[k];
            v = v > 0.f ? v : (__expf(v) - 1.f);  // ELU, fast path
            p2 = fmaf(v, ww[k], p2);
        }
#pragma unroll
        for (int o = 1; o <= 2; o <<= 1) p2 += __shfl_xor(p2, o, 64);
        if (sub == 0 && okn) h2[n] = p2;
    }
}

// ---------------- fused layer2: softmax + aggregate + bias + sigmoid ----------------
__global__ __launch_bounds__(256) void k_agg2(
    const int* __restrict__ csr, const int* __restrict__ off, const int* __restrict__ deg,
    const float* __restrict__ h2,
    const float* __restrict__ ats2, const float* __restrict__ atd2,
    const float* __restrict__ b2, float* __restrict__ out, int N)
{
    int idx = blockIdx.x * 256 + threadIdx.x;
    int n = idx >> 4;
    int l16 = threadIdx.x & 15;
    if (n >= N) return;
    int beg = off[n];
    int end = beg + deg[n];
    float a_s = ats2[0], a_d = atd2[0];
    float adv = h2[n] * a_d;
    float den = 0.f, num = 0.f;
    for (int j = beg + l16; j < end; j += 16) {
        float hs = h2[csr[j]];
        float t = fmaf(hs, a_s, adv);
        t = fmaxf(t, 0.2f * t);
        float ex = __expf(t);
        den += ex;
        num = fmaf(ex, hs, num);
    }
#pragma unroll
    for (int o = 1; o <= 8; o <<= 1) {
        den += __shfl_xor(den, o, 64);
        num += __shfl_xor(num, o, 64);
    }
    if (l16 == 0) {
        float t = num / (den + 1e-16f) + b2[0];
        out[n] = 1.f / (1.f + __expf(-t));
    }
}

extern "C" void kernel_launch(void* const* d_in, const int* in_sizes, int n_in,
                              void* d_out, int out_size, void* d_ws, size_t ws_size,
                              hipStream_t stream)
{
    const float* x    = (const float*)d_in[0];
    const int*   ei   = (const int*)d_in[1];
    const float* W1   = (const float*)d_in[2];
    const float* ats1 = (const float*)d_in[3];
    const float* atd1 = (const float*)d_in[4];
    const float* b1   = (const float*)d_in[5];
    const float* W2   = (const float*)d_in[6];
    const float* ats2 = (const float*)d_in[7];
    const float* atd2 = (const float*)d_in[8];
    const float* b2   = (const float*)d_in[9];
    float* out = (float*)d_out;

    const int N = out_size;            // 100000
    const int E = in_sizes[1] / 2;     // 3200000
    const int Etot = E + N;
    const int NBUK = (N + 255) >> 8;   // 391 (<= MAXBUK)
    const size_t capElems = (size_t)NBUK << CAPLOG;   // 6.4M slots (25.6 MB)

    // workspace layout:
    //   union region: ebuf uint[NBUK<<CAPLOG] (25.6MB)  OVERLAYS  feature block
    //                 {h1b bf16[N*64], as1b bf16[N*8], ad1 f32[N*8], h2 f32[N]} (18MB)
    //   then ints: deg[N] off[N] bkt_cnt[512] csr[capElems] pcnt uint2[N] Wt bf16[64*256]
    char* base = (char*)d_ws;
    uint_t* ebuf = (uint_t*)base;
    ushort_t* h1b  = (ushort_t*)base;
    ushort_t* as1b = h1b + (size_t)N * C1;
    float* ad1 = (float*)(as1b + (size_t)N * NH);
    float* h2  = ad1 + (size_t)N * NH;
    size_t featBytes = (size_t)N * (C1 * 2 + NH * 2 + NH * 4 + 4);
    size_t unionBytes = capElems * sizeof(uint_t);
    if (featBytes > unionBytes) unionBytes = featBytes;
    unionBytes = (unionBytes + 255) & ~(size_t)255;
    int* deg     = (int*)(base + unionBytes);
    int* off     = deg + N;
    int* bkt_cnt = off + N;
    int* csr     = bkt_cnt + MAXBUK;
    uint2* pcnt  = (uint2*)(csr + capElems);         // 800 KB
    ushort_t* wtg = (ushort_t*)(pcnt + N);           // 32 KB global Wt

    k_prep<<<64, 256, 0, stream>>>(W1, wtg, bkt_cnt);
    k_bscatter<<<(Etot + SC_CHUNK - 1) / SC_CHUNK, 512, 0, stream>>>(ei, E, N, NBUK, bkt_cnt, ebuf);
    k_bucket_csr<<<NBUK, 512, 0, stream>>>(ebuf, bkt_cnt, N, deg, off, csr, pcnt);

    k_gemm1<<<(N + 63) / 64, 256, 0, stream>>>(x, wtg, ats1, atd1, h1b, as1b, ad1, N);
    k_agg1<<<AGG_GRID, 256, 0, stream>>>(csr, off, pcnt, as1b, ad1, h1b, b1, W2, h2, N);
    k_agg2<<<(N * 16 + 255) / 256, 256, 0, stream>>>(csr, off, deg, h2, ats2, atd2, b2, out, N);
}

// Round 5
// 330.283 us; speedup vs baseline: 1.1013x; 1.1013x over previous
//
#include <hip/hip_runtime.h>
#include <math.h>

// GAT 2-layer pipeline. CSR-by-dst built per launch via LDS-staged counting
// sort into FIXED-CAPACITY buckets (16384 slots/bucket). Aggregation:
// atomic-free per-node online softmax, bf16 features (absmax ~4e-3 << 1.1e-2
// threshold). Layer-1 GEMM on MFMA (bf16): h^T = W^T . x^T.
// Sizes fixed by reference: F_IN=256, HEADS=8, HID=8 -> C1=64; layer2 1x1.
//
// R5: single-variable A/B vs R2. agg1 is R2 VERBATIM (known 73us, 32 VGPR,
// no spills); the only change is csr ORDERING: k_bucket_csr sorts each dst
// list by src-slice (src/12500 -> 8 slices of 1.6MB h1 each). R2's stride-4
// slot loop then automatically keeps all 4 slots of a node inside one slice
// per iteration and sweeps slices monotonically -> instantaneous cross-block
// gather working set ~3-5 slices (~5-8MB) instead of 14.4MB, with NO
// barriers/persistence/state changes. (R4's spills came from hoisted bb/ww +
// persistent tile loop: WRITE 0.5->43.7MB; both removed by reverting shape.)
#define FIN 256
#define C1  64
#define NH  8
#define HID 8
#define MAXBUK 512        // buckets of 256 nodes; N=100000 -> 391 buckets
#define CAPLOG 14         // fixed bucket capacity 16384 edges
#define SC_CHUNK 8192     // edges per k_bscatter block (512 thr, EPT 16)
#define EPT (SC_CHUNK / 512)
#define NSLICE 8          // src slices for csr ordering
#define SLDIV 12500u      // slice = src / SLDIV (N=100000 -> 8 even slices)

typedef unsigned short ushort_t;
typedef unsigned int uint_t;
typedef __attribute__((ext_vector_type(8))) short short8;   // 8 x bf16 MFMA frag
typedef __attribute__((ext_vector_type(4))) float f32x4;    // MFMA acc

__device__ __forceinline__ ushort_t f2bf(float f) {   // round-to-nearest-even
    uint_t u = __float_as_uint(f);
    u += 0x7fffu + ((u >> 16) & 1u);
    return (ushort_t)(u >> 16);
}
__device__ __forceinline__ uint_t packbf2(float lo, float hi) {
    return (uint_t)f2bf(lo) | ((uint_t)f2bf(hi) << 16);
}
__device__ __forceinline__ float bf_lo(uint_t w) { return __uint_as_float(w << 16); }
__device__ __forceinline__ float bf_hi(uint_t w) { return __uint_as_float(w & 0xffff0000u); }

// ---------------- prep: zero bkt_cnt + transpose W -> global bf16 Wt[64][256] ----------------
__global__ void k_prep(const float* __restrict__ W, ushort_t* __restrict__ Wtg,
                       int* __restrict__ bkt_cnt) {
    int tid = blockIdx.x * 256 + threadIdx.x;
    if (tid < MAXBUK) bkt_cnt[tid] = 0;
    int c = tid >> 8;        // 0..63
    int k = tid & 255;       // 0..255
    Wtg[c * 256 + k] = f2bf(W[k * C1 + c]);
}

// ---------------- bucket scatter: packed edges into fixed-capacity buckets ----------------
__global__ __launch_bounds__(512) void k_bscatter(const int* __restrict__ ei, int E, int N,
                                                  int NBUK, int* __restrict__ bkt_cnt,
                                                  uint_t* __restrict__ ebuf) {
    __shared__ int hist[MAXBUK];
    __shared__ int loff[MAXBUK];     // local exclusive offsets; reused as rank cursor
    __shared__ int delta[MAXBUK];    // global_base - local_offset
    __shared__ int ssum[MAXBUK];
    __shared__ uint_t vals[SC_CHUNK];     // 32 KB
    __shared__ ushort_t buks[SC_CHUNK];   // 16 KB

    const int t = threadIdx.x;
    hist[t] = 0;
    __syncthreads();

    const int Etot = E + N;
    const int base0 = blockIdx.x * SC_CHUNK;
    const int lim = min(base0 + SC_CHUNK, Etot);
    const int cnt = lim - base0;

    uint_t myval[EPT];
    int myb[EPT];
#pragma unroll
    for (int i = 0; i < EPT; ++i) {
        int e = base0 + t + i * 512;
        if (e < lim) {
            int s, d;
            if (e < E) { s = ei[e]; d = ei[E + e]; } else { s = e - E; d = s; }
            myval[i] = ((uint_t)s << 8) | (uint_t)(d & 255);
            myb[i] = d >> 8;
            atomicAdd(&hist[myb[i]], 1);
        } else myb[i] = -1;
    }
    __syncthreads();

    // exclusive scan of hist[0..511] with 512 threads
    int v = hist[t];
    ssum[t] = v;
    __syncthreads();
    for (int o = 1; o < 512; o <<= 1) {
        int add = (t >= o) ? ssum[t - o] : 0;
        __syncthreads();
        ssum[t] += add;
        __syncthreads();
    }
    loff[t] = ssum[t] - v;   // exclusive
    __syncthreads();

    // global reservation: one atomic per touched bucket; base = b<<CAPLOG
    if (t < NBUK) {
        int c = hist[t];
        if (c) delta[t] = (t << CAPLOG) + atomicAdd(&bkt_cnt[t], c) - loff[t];
    }
    __syncthreads();

    // rank into staging (loff doubles as cursor; delta already captured)
#pragma unroll
    for (int i = 0; i < EPT; ++i) {
        if (myb[i] >= 0) {
            int pos = atomicAdd(&loff[myb[i]], 1);
            vals[pos] = myval[i];
            buks[pos] = (ushort_t)myb[i];
        }
    }
    __syncthreads();

    // linear write-out: consecutive i -> consecutive gaddr within each run
    for (int i = t; i < cnt; i += 512)
        ebuf[delta[buks[i]] + i] = vals[i];
}

// ---------------- per-bucket: degrees, offsets, slice-sorted csr scatter ----------------
// One block (512 threads) per bucket. Histogram is (local_node, src_slice) =
// 2048 counters -> csr ordered by (node, slice); deg/off per node unchanged.
__global__ __launch_bounds__(512) void k_bucket_csr(const uint_t* __restrict__ ebuf,
                                                    const int* __restrict__ bkt_cnt, int N,
                                                    int* __restrict__ deg, int* __restrict__ off,
                                                    int* __restrict__ csr) {
    __shared__ int hist[256 * NSLICE];   // 8 KB; counts, then cursors
    __shared__ int ssum[512];
    int b = blockIdx.x;
    int t = threadIdx.x;
    int beg = b << CAPLOG;
    int end = beg + bkt_cnt[b];
    for (int i = t; i < 256 * NSLICE; i += 512) hist[i] = 0;
    __syncthreads();
    for (int j = beg + t; j < end; j += 512) {
        uint_t v = ebuf[j];
        int key = ((v & 255u) << 3) | ((v >> 8) / SLDIV);
        atomicAdd(&hist[key], 1);
    }
    __syncthreads();
    // deg (pure reads of hist)
    if (t < 256) {
        int node = (b << 8) + t;
        if (node < N) {
            int s = 0;
#pragma unroll
            for (int i = 0; i < 8; ++i) s += hist[(t << 3) | i];
            deg[node] = s;
        }
    }
    // scan of 2048: thread t owns hist[4t..4t+3]
    int c0 = hist[4 * t], c1 = hist[4 * t + 1], c2 = hist[4 * t + 2], c3 = hist[4 * t + 3];
    int s4 = c0 + c1 + c2 + c3;
    __syncthreads();              // all reads of counts complete before overwrite
    ssum[t] = s4;
    __syncthreads();
    for (int o = 1; o < 512; o <<= 1) {
        int add = (t >= o) ? ssum[t - o] : 0;
        __syncthreads();
        ssum[t] += add;
        __syncthreads();
    }
    int base = beg + ssum[t] - s4;   // global exclusive prefix (cursor init)
    hist[4 * t]     = base;
    hist[4 * t + 1] = base + c0;
    hist[4 * t + 2] = base + c0 + c1;
    hist[4 * t + 3] = base + c0 + c1 + c2;
    __syncthreads();
    if (t < 256) {
        int node = (b << 8) + t;
        if (node < N) off[node] = hist[t << 3];
    }
    __syncthreads();
    for (int j = beg + t; j < end; j += 512) {
        uint_t v = ebuf[j];
        int key = ((v & 255u) << 3) | ((v >> 8) / SLDIV);
        int pos = atomicAdd(&hist[key], 1);
        csr[pos] = (int)(v >> 8);
    }
}

// ---------------- layer1 GEMM via MFMA + attention terms (bf16 outputs) ----------------
// h^T = W^T . x^T per mfma_f32_16x16x32_bf16 tile so D cols = nodes.
// NO LDS: A-fragments read from global bf16 Wt[64][256] (32KB, L1/L2
// resident). 64 nodes/block -> grid 1563, no staging prologue.
__global__ __launch_bounds__(256) void k_gemm1(
    const float* __restrict__ x, const ushort_t* __restrict__ Wtg,
    const float* __restrict__ att_s, const float* __restrict__ att_d,
    ushort_t* __restrict__ h1b, ushort_t* __restrict__ as1b, float* __restrict__ ad1, int N)
{
    const int t = threadIdx.x;
    const int wv = t >> 6, l = t & 63;
    const int l15 = l & 15, q = l >> 4;
    const int node = blockIdx.x * 64 + wv * 16 + l15;
    const bool ok = node < N;
    const float* xr = x + (size_t)(ok ? node : N - 1) * FIN;

    f32x4 acc[4];   // [ct] : output channels ct*16 + q*4 + 0..3, col = node
#pragma unroll
    for (int ct = 0; ct < 4; ++ct) acc[ct] = (f32x4){0.f, 0.f, 0.f, 0.f};

    for (int kk = 0; kk < 8; ++kk) {
        const int kof = kk * 32 + q * 8;
        short8 af[4];
#pragma unroll
        for (int ct = 0; ct < 4; ++ct)
            af[ct] = *reinterpret_cast<const short8*>(&Wtg[(ct * 16 + l15) * 256 + kof]);
        const float4* xp = reinterpret_cast<const float4*>(xr + kof);
        float4 v0 = xp[0], v1 = xp[1];
        union { short8 s; uint_t u[4]; } bu;
        bu.u[0] = packbf2(v0.x, v0.y);
        bu.u[1] = packbf2(v0.z, v0.w);
        bu.u[2] = packbf2(v1.x, v1.y);
        bu.u[3] = packbf2(v1.z, v1.w);
#pragma unroll
        for (int ct = 0; ct < 4; ++ct)
            acc[ct] = __builtin_amdgcn_mfma_f32_16x16x32_bf16(af[ct], bu.s, acc[ct], 0, 0, 0);
    }

    float4 ats[4], atd4[4];
#pragma unroll
    for (int ct = 0; ct < 4; ++ct) {
        ats[ct]  = *reinterpret_cast<const float4*>(&att_s[ct * 16 + q * 4]);
        atd4[ct] = *reinterpret_cast<const float4*>(&att_d[ct * 16 + q * 4]);
    }
    const int hb = q >> 1;

    float asp[8], adp[8];
#pragma unroll
    for (int h = 0; h < 8; ++h) { asp[h] = 0.f; adp[h] = 0.f; }
#pragma unroll
    for (int ct = 0; ct < 4; ++ct) {
        f32x4 a = acc[ct];
        if (ok) {
            uint2 hv;
            hv.x = packbf2(a[0], a[1]);
            hv.y = packbf2(a[2], a[3]);
            *reinterpret_cast<uint2*>(&h1b[(size_t)node * C1 + ct * 16 + q * 4]) = hv;
        }
        int h = ct * 2 + hb;
        asp[h] = a[0] * ats[ct].x + a[1] * ats[ct].y + a[2] * ats[ct].z + a[3] * ats[ct].w;
        adp[h] = a[0] * atd4[ct].x + a[1] * atd4[ct].y + a[2] * atd4[ct].z + a[3] * atd4[ct].w;
    }
#pragma unroll
    for (int o = 16; o <= 32; o <<= 1) {
#pragma unroll
        for (int h = 0; h < 8; ++h) {
            asp[h] += __shfl_xor(asp[h], o, 64);
            adp[h] += __shfl_xor(adp[h], o, 64);
        }
    }
    if (q == 0 && ok) {
        uint4 aw;
        aw.x = packbf2(asp[0], asp[1]);
        aw.y = packbf2(asp[2], asp[3]);
        aw.z = packbf2(asp[4], asp[5]);
        aw.w = packbf2(asp[6], asp[7]);
        *reinterpret_cast<uint4*>(&as1b[(size_t)node * NH]) = aw;
        *reinterpret_cast<float4*>(&ad1[(size_t)node * NH]) =
            make_float4(adp[0], adp[1], adp[2], adp[3]);
        *reinterpret_cast<float4*>(&ad1[(size_t)node * NH + 4]) =
            make_float4(adp[4], adp[5], adp[6], adp[7]);
    }
}

// ---------------- fused layer1 aggregation + bias/ELU + W2 projection ----------------
// R2 verbatim. 4 nodes per wave, 16 lanes/node: sub = lane&15, slot = sub>>2,
// hp = sub&3. csr is slice-sorted, so the stride-4 slot loop sweeps src
// slices monotonically per node -> smaller instantaneous L2 working set.
__global__ __launch_bounds__(256) void k_agg1(
    const int* __restrict__ csr, const int* __restrict__ off, const int* __restrict__ deg,
    const ushort_t* __restrict__ as1b, const float* __restrict__ ad1,
    const ushort_t* __restrict__ h1b,
    const float* __restrict__ b1, const float* __restrict__ W2,
    float* __restrict__ h2, int N)
{
    int idx = blockIdx.x * 256 + threadIdx.x;
    int n = idx >> 4;
    if (n >= N) return;
    int sub  = threadIdx.x & 15;
    int hp   = sub & 3;
    int slot = sub >> 2;

    int beg = off[n];
    int end = beg + deg[n];

    float adv0 = ad1[(size_t)n * NH + 2 * hp];
    float adv1 = ad1[(size_t)n * NH + 2 * hp + 1];
    float den0 = 0.f, den1 = 0.f;
    float acc[16];
#pragma unroll
    for (int k = 0; k < 16; ++k) acc[k] = 0.f;

    for (int base = beg; base < end; base += 4) {
        int j = base + slot;
        int jj = j < end ? j : end - 1;
        int s = csr[jj];
        uint_t a2 = *reinterpret_cast<const uint_t*>(&as1b[(size_t)s * NH + 2 * hp]);
        float t0 = bf_lo(a2) + adv0;
        float t1 = bf_hi(a2) + adv1;
        t0 = fmaxf(t0, 0.2f * t0);
        t1 = fmaxf(t1, 0.2f * t1);
        bool live = j < end;
        float ex0 = live ? __expf(t0) : 0.f;
        float ex1 = live ? __expf(t1) : 0.f;
        den0 += ex0; den1 += ex1;
        const uint4* hbp = reinterpret_cast<const uint4*>(&h1b[(size_t)s * C1 + hp * 16]);
        uint4 u0 = hbp[0], u1 = hbp[1];
        acc[0]  = fmaf(ex0, bf_lo(u0.x), acc[0]);
        acc[1]  = fmaf(ex0, bf_hi(u0.x), acc[1]);
        acc[2]  = fmaf(ex0, bf_lo(u0.y), acc[2]);
        acc[3]  = fmaf(ex0, bf_hi(u0.y), acc[3]);
        acc[4]  = fmaf(ex0, bf_lo(u0.z), acc[4]);
        acc[5]  = fmaf(ex0, bf_hi(u0.z), acc[5]);
        acc[6]  = fmaf(ex0, bf_lo(u0.w), acc[6]);
        acc[7]  = fmaf(ex0, bf_hi(u0.w), acc[7]);
        acc[8]  = fmaf(ex1, bf_lo(u1.x), acc[8]);
        acc[9]  = fmaf(ex1, bf_hi(u1.x), acc[9]);
        acc[10] = fmaf(ex1, bf_lo(u1.y), acc[10]);
        acc[11] = fmaf(ex1, bf_hi(u1.y), acc[11]);
        acc[12] = fmaf(ex1, bf_lo(u1.z), acc[12]);
        acc[13] = fmaf(ex1, bf_hi(u1.z), acc[13]);
        acc[14] = fmaf(ex1, bf_lo(u1.w), acc[14]);
        acc[15] = fmaf(ex1, bf_hi(u1.w), acc[15]);
    }

#pragma unroll
    for (int o = 4; o <= 8; o <<= 1) {
        den0 += __shfl_xor(den0, o, 64);
        den1 += __shfl_xor(den1, o, 64);
#pragma unroll
        for (int k = 0; k < 16; ++k) acc[k] += __shfl_xor(acc[k], o, 64);
    }

    float inv0 = 1.f / (den0 + 1e-16f);
    float inv1 = 1.f / (den1 + 1e-16f);
    const float4* bp = reinterpret_cast<const float4*>(&b1[hp * 16]);
    const float4* wp = reinterpret_cast<const float4*>(&W2[hp * 16]);
    float bb[16], ww[16];
#pragma unroll
    for (int i = 0; i < 4; ++i) {
        float4 b4 = bp[i], w4 = wp[i];
        bb[4 * i] = b4.x; bb[4 * i + 1] = b4.y; bb[4 * i + 2] = b4.z; bb[4 * i + 3] = b4.w;
        ww[4 * i] = w4.x; ww[4 * i + 1] = w4.y; ww[4 * i + 2] = w4.z; ww[4 * i + 3] = w4.w;
    }
    float p = 0.f;
#pragma unroll
    for (int k = 0; k < 16; ++k) {
        float inv = (k < 8) ? inv0 : inv1;
        float v = acc[k] * inv + bb[k];
        v = v > 0.f ? v : (__expf(v) - 1.f);  // ELU, fast path
        p = fmaf(v, ww[k], p);
    }
#pragma unroll
    for (int o = 1; o <= 2; o <<= 1) p += __shfl_xor(p, o, 64);
    if (sub == 0) h2[n] = p;
}

// ---------------- fused layer2: softmax + aggregate + bias + sigmoid ----------------
__global__ __launch_bounds__(256) void k_agg2(
    const int* __restrict__ csr, const int* __restrict__ off, const int* __restrict__ deg,
    const float* __restrict__ h2,
    const float* __restrict__ ats2, const float* __restrict__ atd2,
    const float* __restrict__ b2, float* __restrict__ out, int N)
{
    int idx = blockIdx.x * 256 + threadIdx.x;
    int n = idx >> 4;
    int l16 = threadIdx.x & 15;
    if (n >= N) return;
    int beg = off[n];
    int end = beg + deg[n];
    float a_s = ats2[0], a_d = atd2[0];
    float adv = h2[n] * a_d;
    float den = 0.f, num = 0.f;
    for (int j = beg + l16; j < end; j += 16) {
        float hs = h2[csr[j]];
        float t = fmaf(hs, a_s, adv);
        t = fmaxf(t, 0.2f * t);
        float ex = __expf(t);
        den += ex;
        num = fmaf(ex, hs, num);
    }
#pragma unroll
    for (int o = 1; o <= 8; o <<= 1) {
        den += __shfl_xor(den, o, 64);
        num += __shfl_xor(num, o, 64);
    }
    if (l16 == 0) {
        float t = num / (den + 1e-16f) + b2[0];
        out[n] = 1.f / (1.f + __expf(-t));
    }
}

extern "C" void kernel_launch(void* const* d_in, const int* in_sizes, int n_in,
                              void* d_out, int out_size, void* d_ws, size_t ws_size,
                              hipStream_t stream)
{
    const float* x    = (const float*)d_in[0];
    const int*   ei   = (const int*)d_in[1];
    const float* W1   = (const float*)d_in[2];
    const float* ats1 = (const float*)d_in[3];
    const float* atd1 = (const float*)d_in[4];
    const float* b1   = (const float*)d_in[5];
    const float* W2   = (const float*)d_in[6];
    const float* ats2 = (const float*)d_in[7];
    const float* atd2 = (const float*)d_in[8];
    const float* b2   = (const float*)d_in[9];
    float* out = (float*)d_out;

    const int N = out_size;            // 100000
    const int E = in_sizes[1] / 2;     // 3200000
    const int Etot = E + N;
    const int NBUK = (N + 255) >> 8;   // 391 (<= MAXBUK)
    const size_t capElems = (size_t)NBUK << CAPLOG;   // 6.4M slots (25.6 MB)

    // workspace layout:
    //   union region: ebuf uint[NBUK<<CAPLOG] (25.6MB)  OVERLAYS  feature block
    //                 {h1b bf16[N*64], as1b bf16[N*8], ad1 f32[N*8], h2 f32[N]} (18MB)
    //   then ints: deg[N] off[N] bkt_cnt[512] csr[capElems]  then Wt bf16[64*256]
    char* base = (char*)d_ws;
    uint_t* ebuf = (uint_t*)base;
    ushort_t* h1b  = (ushort_t*)base;
    ushort_t* as1b = h1b + (size_t)N * C1;
    float* ad1 = (float*)(as1b + (size_t)N * NH);
    float* h2  = ad1 + (size_t)N * NH;
    size_t featBytes = (size_t)N * (C1 * 2 + NH * 2 + NH * 4 + 4);
    size_t unionBytes = capElems * sizeof(uint_t);
    if (featBytes > unionBytes) unionBytes = featBytes;
    unionBytes = (unionBytes + 255) & ~(size_t)255;
    int* deg     = (int*)(base + unionBytes);
    int* off     = deg + N;
    int* bkt_cnt = off + N;
    int* csr     = bkt_cnt + MAXBUK;
    ushort_t* wtg = (ushort_t*)(csr + capElems);   // 32 KB global Wt

    k_prep<<<64, 256, 0, stream>>>(W1, wtg, bkt_cnt);
    k_bscatter<<<(Etot + SC_CHUNK - 1) / SC_CHUNK, 512, 0, stream>>>(ei, E, N, NBUK, bkt_cnt, ebuf);
    k_bucket_csr<<<NBUK, 512, 0, stream>>>(ebuf, bkt_cnt, N, deg, off, csr);

    k_gemm1<<<(N + 63) / 64, 256, 0, stream>>>(x, wtg, ats1, atd1, h1b, as1b, ad1, N);
    k_agg1<<<(N * 16 + 255) / 256, 256, 0, stream>>>(csr, off, deg, as1b, ad1, h1b, b1, W2, h2, N);
    k_agg2<<<(N * 16 + 255) / 256, 256, 0, stream>>>(csr, off, deg, h2, ats2, atd2, b2, out, N);
}

// Round 6
// 330.027 us; speedup vs baseline: 1.1021x; 1.0008x over previous
//
#include <hip/hip_runtime.h>
#include <math.h>

// GAT 2-layer pipeline. CSR-by-dst built per launch via LDS-staged counting
// sort into FIXED-CAPACITY buckets (16384 slots/bucket). Aggregation:
// atomic-free per-node online softmax, bf16 features (absmax ~4e-3 << 1.1e-2
// threshold). Layer-1 GEMM on MFMA (bf16): h^T = W^T . x^T.
// Sizes fixed by reference: F_IN=256, HEADS=8, HID=8 -> C1=64; layer2 1x1.
//
// R6: slice-granularity probe. R5 proved csr src-slice ordering cuts agg1
// re-fetch (224->193MB, 73.5->67.2us) with agg1's code unchanged. The
// remaining ~62MB over compulsory comes from dispatch-generation mixing
// (resident blocks uniformly cover all sweep positions); finer slices shrink
// each slice band's footprint so a fetched line's sharing window fits L2
// residency (~10us/XCD). 8 -> 32 slices (0.4MB h1/slice). Again a
// csr-ORDERING-only change: agg1 identical (32 VGPR, no spills);
// k_bucket_csr histogram grows to 256x32 = 8192 counters (32KB LDS,
// 16 counters/thread scan) - one-shot 391-block kernel.
#define FIN 256
#define C1  64
#define NH  8
#define HID 8
#define MAXBUK 512        // buckets of 256 nodes; N=100000 -> 391 buckets
#define CAPLOG 14         // fixed bucket capacity 16384 edges
#define SC_CHUNK 8192     // edges per k_bscatter block (512 thr, EPT 16)
#define EPT (SC_CHUNK / 512)
#define NSLICE 32         // src slices for csr ordering
#define SLDIV 3125u       // slice = src / SLDIV (N=100000 -> 32 even slices)

typedef unsigned short ushort_t;
typedef unsigned int uint_t;
typedef __attribute__((ext_vector_type(8))) short short8;   // 8 x bf16 MFMA frag
typedef __attribute__((ext_vector_type(4))) float f32x4;    // MFMA acc

__device__ __forceinline__ ushort_t f2bf(float f) {   // round-to-nearest-even
    uint_t u = __float_as_uint(f);
    u += 0x7fffu + ((u >> 16) & 1u);
    return (ushort_t)(u >> 16);
}
__device__ __forceinline__ uint_t packbf2(float lo, float hi) {
    return (uint_t)f2bf(lo) | ((uint_t)f2bf(hi) << 16);
}
__device__ __forceinline__ float bf_lo(uint_t w) { return __uint_as_float(w << 16); }
__device__ __forceinline__ float bf_hi(uint_t w) { return __uint_as_float(w & 0xffff0000u); }

// ---------------- prep: zero bkt_cnt + transpose W -> global bf16 Wt[64][256] ----------------
__global__ void k_prep(const float* __restrict__ W, ushort_t* __restrict__ Wtg,
                       int* __restrict__ bkt_cnt) {
    int tid = blockIdx.x * 256 + threadIdx.x;
    if (tid < MAXBUK) bkt_cnt[tid] = 0;
    int c = tid >> 8;        // 0..63
    int k = tid & 255;       // 0..255
    Wtg[c * 256 + k] = f2bf(W[k * C1 + c]);
}

// ---------------- bucket scatter: packed edges into fixed-capacity buckets ----------------
__global__ __launch_bounds__(512) void k_bscatter(const int* __restrict__ ei, int E, int N,
                                                  int NBUK, int* __restrict__ bkt_cnt,
                                                  uint_t* __restrict__ ebuf) {
    __shared__ int hist[MAXBUK];
    __shared__ int loff[MAXBUK];     // local exclusive offsets; reused as rank cursor
    __shared__ int delta[MAXBUK];    // global_base - local_offset
    __shared__ int ssum[MAXBUK];
    __shared__ uint_t vals[SC_CHUNK];     // 32 KB
    __shared__ ushort_t buks[SC_CHUNK];   // 16 KB

    const int t = threadIdx.x;
    hist[t] = 0;
    __syncthreads();

    const int Etot = E + N;
    const int base0 = blockIdx.x * SC_CHUNK;
    const int lim = min(base0 + SC_CHUNK, Etot);
    const int cnt = lim - base0;

    uint_t myval[EPT];
    int myb[EPT];
#pragma unroll
    for (int i = 0; i < EPT; ++i) {
        int e = base0 + t + i * 512;
        if (e < lim) {
            int s, d;
            if (e < E) { s = ei[e]; d = ei[E + e]; } else { s = e - E; d = s; }
            myval[i] = ((uint_t)s << 8) | (uint_t)(d & 255);
            myb[i] = d >> 8;
            atomicAdd(&hist[myb[i]], 1);
        } else myb[i] = -1;
    }
    __syncthreads();

    // exclusive scan of hist[0..511] with 512 threads
    int v = hist[t];
    ssum[t] = v;
    __syncthreads();
    for (int o = 1; o < 512; o <<= 1) {
        int add = (t >= o) ? ssum[t - o] : 0;
        __syncthreads();
        ssum[t] += add;
        __syncthreads();
    }
    loff[t] = ssum[t] - v;   // exclusive
    __syncthreads();

    // global reservation: one atomic per touched bucket; base = b<<CAPLOG
    if (t < NBUK) {
        int c = hist[t];
        if (c) delta[t] = (t << CAPLOG) + atomicAdd(&bkt_cnt[t], c) - loff[t];
    }
    __syncthreads();

    // rank into staging (loff doubles as cursor; delta already captured)
#pragma unroll
    for (int i = 0; i < EPT; ++i) {
        if (myb[i] >= 0) {
            int pos = atomicAdd(&loff[myb[i]], 1);
            vals[pos] = myval[i];
            buks[pos] = (ushort_t)myb[i];
        }
    }
    __syncthreads();

    // linear write-out: consecutive i -> consecutive gaddr within each run
    for (int i = t; i < cnt; i += 512)
        ebuf[delta[buks[i]] + i] = vals[i];
}

// ---------------- per-bucket: degrees, offsets, slice-sorted csr scatter ----------------
// One block (512 threads) per bucket. Histogram is (local_node, src_slice) =
// 256 x 32 = 8192 counters (32KB LDS) -> csr ordered by (node, slice).
// Scan: 16 counters/thread sequential + 512-wide block scan.
__global__ __launch_bounds__(512) void k_bucket_csr(const uint_t* __restrict__ ebuf,
                                                    const int* __restrict__ bkt_cnt, int N,
                                                    int* __restrict__ deg, int* __restrict__ off,
                                                    int* __restrict__ csr) {
    __shared__ int hist[256 * NSLICE];   // 32 KB; counts, then cursors
    __shared__ int ssum[512];
    int b = blockIdx.x;
    int t = threadIdx.x;
    int beg = b << CAPLOG;
    int end = beg + bkt_cnt[b];
    for (int i = t; i < 256 * NSLICE; i += 512) hist[i] = 0;
    __syncthreads();
    for (int j = beg + t; j < end; j += 512) {
        uint_t v = ebuf[j];
        int key = ((v & 255u) << 5) | ((v >> 8) / SLDIV);
        atomicAdd(&hist[key], 1);
    }
    __syncthreads();
    // deg (pure reads of hist)
    if (t < 256) {
        int node = (b << 8) + t;
        if (node < N) {
            int s = 0;
#pragma unroll
            for (int i = 0; i < NSLICE; ++i) s += hist[(t << 5) | i];
            deg[node] = s;
        }
    }
    // scan of 8192: thread t owns hist[16t..16t+15]
    int c[16];
    int s16 = 0;
#pragma unroll
    for (int i = 0; i < 16; ++i) { c[i] = hist[16 * t + i]; s16 += c[i]; }
    __syncthreads();              // all reads of counts complete before overwrite
    ssum[t] = s16;
    __syncthreads();
    for (int o = 1; o < 512; o <<= 1) {
        int add = (t >= o) ? ssum[t - o] : 0;
        __syncthreads();
        ssum[t] += add;
        __syncthreads();
    }
    int base = beg + ssum[t] - s16;   // global exclusive prefix (cursor init)
#pragma unroll
    for (int i = 0; i < 16; ++i) {
        hist[16 * t + i] = base;
        base += c[i];
    }
    __syncthreads();
    if (t < 256) {
        int node = (b << 8) + t;
        if (node < N) off[node] = hist[t << 5];
    }
    __syncthreads();
    for (int j = beg + t; j < end; j += 512) {
        uint_t v = ebuf[j];
        int key = ((v & 255u) << 5) | ((v >> 8) / SLDIV);
        int pos = atomicAdd(&hist[key], 1);
        csr[pos] = (int)(v >> 8);
    }
}

// ---------------- layer1 GEMM via MFMA + attention terms (bf16 outputs) ----------------
// h^T = W^T . x^T per mfma_f32_16x16x32_bf16 tile so D cols = nodes.
// NO LDS: A-fragments read from global bf16 Wt[64][256] (32KB, L1/L2
// resident). 64 nodes/block -> grid 1563, no staging prologue.
__global__ __launch_bounds__(256) void k_gemm1(
    const float* __restrict__ x, const ushort_t* __restrict__ Wtg,
    const float* __restrict__ att_s, const float* __restrict__ att_d,
    ushort_t* __restrict__ h1b, ushort_t* __restrict__ as1b, float* __restrict__ ad1, int N)
{
    const int t = threadIdx.x;
    const int wv = t >> 6, l = t & 63;
    const int l15 = l & 15, q = l >> 4;
    const int node = blockIdx.x * 64 + wv * 16 + l15;
    const bool ok = node < N;
    const float* xr = x + (size_t)(ok ? node : N - 1) * FIN;

    f32x4 acc[4];   // [ct] : output channels ct*16 + q*4 + 0..3, col = node
#pragma unroll
    for (int ct = 0; ct < 4; ++ct) acc[ct] = (f32x4){0.f, 0.f, 0.f, 0.f};

    for (int kk = 0; kk < 8; ++kk) {
        const int kof = kk * 32 + q * 8;
        short8 af[4];
#pragma unroll
        for (int ct = 0; ct < 4; ++ct)
            af[ct] = *reinterpret_cast<const short8*>(&Wtg[(ct * 16 + l15) * 256 + kof]);
        const float4* xp = reinterpret_cast<const float4*>(xr + kof);
        float4 v0 = xp[0], v1 = xp[1];
        union { short8 s; uint_t u[4]; } bu;
        bu.u[0] = packbf2(v0.x, v0.y);
        bu.u[1] = packbf2(v0.z, v0.w);
        bu.u[2] = packbf2(v1.x, v1.y);
        bu.u[3] = packbf2(v1.z, v1.w);
#pragma unroll
        for (int ct = 0; ct < 4; ++ct)
            acc[ct] = __builtin_amdgcn_mfma_f32_16x16x32_bf16(af[ct], bu.s, acc[ct], 0, 0, 0);
    }

    float4 ats[4], atd4[4];
#pragma unroll
    for (int ct = 0; ct < 4; ++ct) {
        ats[ct]  = *reinterpret_cast<const float4*>(&att_s[ct * 16 + q * 4]);
        atd4[ct] = *reinterpret_cast<const float4*>(&att_d[ct * 16 + q * 4]);
    }
    const int hb = q >> 1;

    float asp[8], adp[8];
#pragma unroll
    for (int h = 0; h < 8; ++h) { asp[h] = 0.f; adp[h] = 0.f; }
#pragma unroll
    for (int ct = 0; ct < 4; ++ct) {
        f32x4 a = acc[ct];
        if (ok) {
            uint2 hv;
            hv.x = packbf2(a[0], a[1]);
            hv.y = packbf2(a[2], a[3]);
            *reinterpret_cast<uint2*>(&h1b[(size_t)node * C1 + ct * 16 + q * 4]) = hv;
        }
        int h = ct * 2 + hb;
        asp[h] = a[0] * ats[ct].x + a[1] * ats[ct].y + a[2] * ats[ct].z + a[3] * ats[ct].w;
        adp[h] = a[0] * atd4[ct].x + a[1] * atd4[ct].y + a[2] * atd4[ct].z + a[3] * atd4[ct].w;
    }
#pragma unroll
    for (int o = 16; o <= 32; o <<= 1) {
#pragma unroll
        for (int h = 0; h < 8; ++h) {
            asp[h] += __shfl_xor(asp[h], o, 64);
            adp[h] += __shfl_xor(adp[h], o, 64);
        }
    }
    if (q == 0 && ok) {
        uint4 aw;
        aw.x = packbf2(asp[0], asp[1]);
        aw.y = packbf2(asp[2], asp[3]);
        aw.z = packbf2(asp[4], asp[5]);
        aw.w = packbf2(asp[6], asp[7]);
        *reinterpret_cast<uint4*>(&as1b[(size_t)node * NH]) = aw;
        *reinterpret_cast<float4*>(&ad1[(size_t)node * NH]) =
            make_float4(adp[0], adp[1], adp[2], adp[3]);
        *reinterpret_cast<float4*>(&ad1[(size_t)node * NH + 4]) =
            make_float4(adp[4], adp[5], adp[6], adp[7]);
    }
}

// ---------------- fused layer1 aggregation + bias/ELU + W2 projection ----------------
// R2 verbatim. 4 nodes per wave, 16 lanes/node: sub = lane&15, slot = sub>>2,
// hp = sub&3. csr is slice-sorted, so the stride-4 slot loop sweeps src
// slices monotonically per node -> smaller instantaneous L2 working set.
__global__ __launch_bounds__(256) void k_agg1(
    const int* __restrict__ csr, const int* __restrict__ off, const int* __restrict__ deg,
    const ushort_t* __restrict__ as1b, const float* __restrict__ ad1,
    const ushort_t* __restrict__ h1b,
    const float* __restrict__ b1, const float* __restrict__ W2,
    float* __restrict__ h2, int N)
{
    int idx = blockIdx.x * 256 + threadIdx.x;
    int n = idx >> 4;
    if (n >= N) return;
    int sub  = threadIdx.x & 15;
    int hp   = sub & 3;
    int slot = sub >> 2;

    int beg = off[n];
    int end = beg + deg[n];

    float adv0 = ad1[(size_t)n * NH + 2 * hp];
    float adv1 = ad1[(size_t)n * NH + 2 * hp + 1];
    float den0 = 0.f, den1 = 0.f;
    float acc[16];
#pragma unroll
    for (int k = 0; k < 16; ++k) acc[k] = 0.f;

    for (int base = beg; base < end; base += 4) {
        int j = base + slot;
        int jj = j < end ? j : end - 1;
        int s = csr[jj];
        uint_t a2 = *reinterpret_cast<const uint_t*>(&as1b[(size_t)s * NH + 2 * hp]);
        float t0 = bf_lo(a2) + adv0;
        float t1 = bf_hi(a2) + adv1;
        t0 = fmaxf(t0, 0.2f * t0);
        t1 = fmaxf(t1, 0.2f * t1);
        bool live = j < end;
        float ex0 = live ? __expf(t0) : 0.f;
        float ex1 = live ? __expf(t1) : 0.f;
        den0 += ex0; den1 += ex1;
        const uint4* hbp = reinterpret_cast<const uint4*>(&h1b[(size_t)s * C1 + hp * 16]);
        uint4 u0 = hbp[0], u1 = hbp[1];
        acc[0]  = fmaf(ex0, bf_lo(u0.x), acc[0]);
        acc[1]  = fmaf(ex0, bf_hi(u0.x), acc[1]);
        acc[2]  = fmaf(ex0, bf_lo(u0.y), acc[2]);
        acc[3]  = fmaf(ex0, bf_hi(u0.y), acc[3]);
        acc[4]  = fmaf(ex0, bf_lo(u0.z), acc[4]);
        acc[5]  = fmaf(ex0, bf_hi(u0.z), acc[5]);
        acc[6]  = fmaf(ex0, bf_lo(u0.w), acc[6]);
        acc[7]  = fmaf(ex0, bf_hi(u0.w), acc[7]);
        acc[8]  = fmaf(ex1, bf_lo(u1.x), acc[8]);
        acc[9]  = fmaf(ex1, bf_hi(u1.x), acc[9]);
        acc[10] = fmaf(ex1, bf_lo(u1.y), acc[10]);
        acc[11] = fmaf(ex1, bf_hi(u1.y), acc[11]);
        acc[12] = fmaf(ex1, bf_lo(u1.z), acc[12]);
        acc[13] = fmaf(ex1, bf_hi(u1.z), acc[13]);
        acc[14] = fmaf(ex1, bf_lo(u1.w), acc[14]);
        acc[15] = fmaf(ex1, bf_hi(u1.w), acc[15]);
    }

#pragma unroll
    for (int o = 4; o <= 8; o <<= 1) {
        den0 += __shfl_xor(den0, o, 64);
        den1 += __shfl_xor(den1, o, 64);
#pragma unroll
        for (int k = 0; k < 16; ++k) acc[k] += __shfl_xor(acc[k], o, 64);
    }

    float inv0 = 1.f / (den0 + 1e-16f);
    float inv1 = 1.f / (den1 + 1e-16f);
    const float4* bp = reinterpret_cast<const float4*>(&b1[hp * 16]);
    const float4* wp = reinterpret_cast<const float4*>(&W2[hp * 16]);
    float bb[16], ww[16];
#pragma unroll
    for (int i = 0; i < 4; ++i) {
        float4 b4 = bp[i], w4 = wp[i];
        bb[4 * i] = b4.x; bb[4 * i + 1] = b4.y; bb[4 * i + 2] = b4.z; bb[4 * i + 3] = b4.w;
        ww[4 * i] = w4.x; ww[4 * i + 1] = w4.y; ww[4 * i + 2] = w4.z; ww[4 * i + 3] = w4.w;
    }
    float p = 0.f;
#pragma unroll
    for (int k = 0; k < 16; ++k) {
        float inv = (k < 8) ? inv0 : inv1;
        float v = acc[k] * inv + bb[k];
        v = v > 0.f ? v : (__expf(v) - 1.f);  // ELU, fast path
        p = fmaf(v, ww[k], p);
    }
#pragma unroll
    for (int o = 1; o <= 2; o <<= 1) p += __shfl_xor(p, o, 64);
    if (sub == 0) h2[n] = p;
}

// ---------------- fused layer2: softmax + aggregate + bias + sigmoid ----------------
__global__ __launch_bounds__(256) void k_agg2(
    const int* __restrict__ csr, const int* __restrict__ off, const int* __restrict__ deg,
    const float* __restrict__ h2,
    const float* __restrict__ ats2, const float* __restrict__ atd2,
    const float* __restrict__ b2, float* __restrict__ out, int N)
{
    int idx = blockIdx.x * 256 + threadIdx.x;
    int n = idx >> 4;
    int l16 = threadIdx.x & 15;
    if (n >= N) return;
    int beg = off[n];
    int end = beg + deg[n];
    float a_s = ats2[0], a_d = atd2[0];
    float adv = h2[n] * a_d;
    float den = 0.f, num = 0.f;
    for (int j = beg + l16; j < end; j += 16) {
        float hs = h2[csr[j]];
        float t = fmaf(hs, a_s, adv);
        t = fmaxf(t, 0.2f * t);
        float ex = __expf(t);
        den += ex;
        num = fmaf(ex, hs, num);
    }
#pragma unroll
    for (int o = 1; o <= 8; o <<= 1) {
        den += __shfl_xor(den, o, 64);
        num += __shfl_xor(num, o, 64);
    }
    if (l16 == 0) {
        float t = num / (den + 1e-16f) + b2[0];
        out[n] = 1.f / (1.f + __expf(-t));
    }
}

extern "C" void kernel_launch(void* const* d_in, const int* in_sizes, int n_in,
                              void* d_out, int out_size, void* d_ws, size_t ws_size,
                              hipStream_t stream)
{
    const float* x    = (const float*)d_in[0];
    const int*   ei   = (const int*)d_in[1];
    const float* W1   = (const float*)d_in[2];
    const float* ats1 = (const float*)d_in[3];
    const float* atd1 = (const float*)d_in[4];
    const float* b1   = (const float*)d_in[5];
    const float* W2   = (const float*)d_in[6];
    const float* ats2 = (const float*)d_in[7];
    const float* atd2 = (const float*)d_in[8];
    const float* b2   = (const float*)d_in[9];
    float* out = (float*)d_out;

    const int N = out_size;            // 100000
    const int E = in_sizes[1] / 2;     // 3200000
    const int Etot = E + N;
    const int NBUK = (N + 255) >> 8;   // 391 (<= MAXBUK)
    const size_t capElems = (size_t)NBUK << CAPLOG;   // 6.4M slots (25.6 MB)

    // workspace layout:
    //   union region: ebuf uint[NBUK<<CAPLOG] (25.6MB)  OVERLAYS  feature block
    //                 {h1b bf16[N*64], as1b bf16[N*8], ad1 f32[N*8], h2 f32[N]} (18MB)
    //   then ints: deg[N] off[N] bkt_cnt[512] csr[capElems]  then Wt bf16[64*256]
    char* base = (char*)d_ws;
    uint_t* ebuf = (uint_t*)base;
    ushort_t* h1b  = (ushort_t*)base;
    ushort_t* as1b = h1b + (size_t)N * C1;
    float* ad1 = (float*)(as1b + (size_t)N * NH);
    float* h2  = ad1 + (size_t)N * NH;
    size_t featBytes = (size_t)N * (C1 * 2 + NH * 2 + NH * 4 + 4);
    size_t unionBytes = capElems * sizeof(uint_t);
    if (featBytes > unionBytes) unionBytes = featBytes;
    unionBytes = (unionBytes + 255) & ~(size_t)255;
    int* deg     = (int*)(base + unionBytes);
    int* off     = deg + N;
    int* bkt_cnt = off + N;
    int* csr     = bkt_cnt + MAXBUK;
    ushort_t* wtg = (ushort_t*)(csr + capElems);   // 32 KB global Wt

    k_prep<<<64, 256, 0, stream>>>(W1, wtg, bkt_cnt);
    k_bscatter<<<(Etot + SC_CHUNK - 1) / SC_CHUNK, 512, 0, stream>>>(ei, E, N, NBUK, bkt_cnt, ebuf);
    k_bucket_csr<<<NBUK, 512, 0, stream>>>(ebuf, bkt_cnt, N, deg, off, csr);

    k_gemm1<<<(N + 63) / 64, 256, 0, stream>>>(x, wtg, ats1, atd1, h1b, as1b, ad1, N);
    k_agg1<<<(N * 16 + 255) / 256, 256, 0, stream>>>(csr, off, deg, as1b, ad1, h1b, b1, W2, h2, N);
    k_agg2<<<(N * 16 + 255) / 256, 256, 0, stream>>>(csr, off, deg, h2, ats2, atd2, b2, out, N);
}

// Round 7
// 328.838 us; speedup vs baseline: 1.1061x; 1.0036x over previous
//
#include <hip/hip_runtime.h>
#include <math.h>

// GAT 2-layer pipeline. CSR-by-dst built per launch via LDS-staged counting
// sort into FIXED-CAPACITY buckets (16384 slots/bucket). Aggregation:
// atomic-free per-node online softmax, bf16 features (absmax ~4e-3 << 1.1e-2
// threshold). Layer-1 GEMM on MFMA (bf16): h^T = W^T . x^T.
// Sizes fixed by reference: F_IN=256, HEADS=8, HID=8 -> C1=64; layer2 1x1.
//
// R7: the mid-tier (bscatter + bucket_csr + gemm1 ~ 160-175us combined, each
// <67us so invisible in top-5) is now bigger than agg1 (67.8us, at its
// ordering-structural floor per R6's null). Two fixes, agg1 untouched:
// (a) OVERLAP: gemm1 is independent of the CSR build -> fuse as fat kernels:
//     fatA = bscatter-blocks ++ gemm1-blocks(nodes 0..50048),
//     fatB = bucket_csr-blocks ++ gemm1-blocks(nodes 50048..N).
//     Kernel boundary keeps the bscatter->bucket_csr dependency; gemm1 hides
//     under both. CSR blocks dispatched first (critical path).
// (b) wave-shfl scans (1 barrier) replace 18-barrier Hillis-Steele in both
//     CSR kernels; bscatter LDS 56->52KB (delta folded into hist) -> 3 blk/CU.
// NSLICE reverted to 8 (R6: 32 slices = null for agg1, costs LDS/scan).
#define FIN 256
#define C1  64
#define NH  8
#define HID 8
#define MAXBUK 512        // buckets of 256 nodes; N=100000 -> 391 buckets
#define CAPLOG 14         // fixed bucket capacity 16384 edges
#define SC_CHUNK 8192     // edges per bscatter block (512 thr, EPT 16)
#define EPT (SC_CHUNK / 512)
#define NSLICE 8          // src slices for csr ordering (agg1 L2 phasing)
#define SLDIV 12500u      // slice = src / SLDIV (N=100000 -> 8 even slices)

typedef unsigned short ushort_t;
typedef unsigned int uint_t;
typedef __attribute__((ext_vector_type(8))) short short8;   // 8 x bf16 MFMA frag
typedef __attribute__((ext_vector_type(4))) float f32x4;    // MFMA acc

__device__ __forceinline__ ushort_t f2bf(float f) {   // round-to-nearest-even
    uint_t u = __float_as_uint(f);
    u += 0x7fffu + ((u >> 16) & 1u);
    return (ushort_t)(u >> 16);
}
__device__ __forceinline__ uint_t packbf2(float lo, float hi) {
    return (uint_t)f2bf(lo) | ((uint_t)f2bf(hi) << 16);
}
__device__ __forceinline__ float bf_lo(uint_t w) { return __uint_as_float(w << 16); }
__device__ __forceinline__ float bf_hi(uint_t w) { return __uint_as_float(w & 0xffff0000u); }

// block-wide (512 thr) exclusive scan: shfl wave-scan + 8-entry LDS fixup.
// ONE barrier (vs 18 for Hillis-Steele). Must be called by all 512 threads.
__device__ __forceinline__ int exscan512(int v, int* lds8, int t) {
    int lane = t & 63, w = t >> 6;
    int sc = v;
#pragma unroll
    for (int o = 1; o < 64; o <<= 1) {
        int u = __shfl_up(sc, o, 64);
        if (lane >= o) sc += u;
    }
    if (lane == 63) lds8[w] = sc;
    __syncthreads();
    int woff = 0;
#pragma unroll
    for (int i = 0; i < 8; ++i) woff += (i < w) ? lds8[i] : 0;
    return woff + sc - v;
}

// ---------------- prep: zero bkt_cnt + transpose W -> global bf16 Wt[64][256] ----------------
__global__ void k_prep(const float* __restrict__ W, ushort_t* __restrict__ Wtg,
                       int* __restrict__ bkt_cnt) {
    int tid = blockIdx.x * 256 + threadIdx.x;
    if (tid < MAXBUK) bkt_cnt[tid] = 0;
    int c = tid >> 8;        // 0..63
    int k = tid & 255;       // 0..255
    Wtg[c * 256 + k] = f2bf(W[k * C1 + c]);
}

// ---------------- device body: bucket scatter (one 8192-edge chunk) ----------------
// LDS layout in smem (53312 B total):
//   hist  [0,2048)      512 ints: counts, then per-bucket delta after reservation
//   loff  [2048,4096)   512 ints: exclusive offsets, then rank cursors
//   lds8  [4096,4160)   scan fixup (+pad)
//   vals  [4160,36928)  8192 uints
//   buks  [36928,53312) 8192 ushorts
__device__ void dev_bscatter(const int* __restrict__ ei, int E, int N, int NBUK,
                             int* __restrict__ bkt_cnt, uint_t* __restrict__ ebuf,
                             char* smem, int bid) {
    int* hist = (int*)smem;
    int* loff = (int*)(smem + 2048);
    int* lds8 = (int*)(smem + 4096);
    uint_t* vals = (uint_t*)(smem + 4160);
    ushort_t* buks = (ushort_t*)(smem + 36928);

    const int t = threadIdx.x;
    hist[t] = 0;
    __syncthreads();

    const int Etot = E + N;
    const int base0 = bid * SC_CHUNK;
    const int lim = min(base0 + SC_CHUNK, Etot);
    const int cnt = lim - base0;

    uint_t myval[EPT];
    int myb[EPT];
#pragma unroll
    for (int i = 0; i < EPT; ++i) {
        int e = base0 + t + i * 512;
        if (e < lim) {
            int s, d;
            if (e < E) { s = ei[e]; d = ei[E + e]; } else { s = e - E; d = s; }
            myval[i] = ((uint_t)s << 8) | (uint_t)(d & 255);
            myb[i] = d >> 8;
            atomicAdd(&hist[myb[i]], 1);
        } else myb[i] = -1;
    }
    __syncthreads();

    // exclusive scan of hist (1 barrier)
    int v = hist[t];
    int ex = exscan512(v, lds8, t);
    loff[t] = ex;
    __syncthreads();

    // global reservation; delta overwrites hist[t] (count no longer needed)
    if (t < NBUK) {
        int c = hist[t];
        if (c) hist[t] = (t << CAPLOG) + atomicAdd(&bkt_cnt[t], c) - ex;
    }
    __syncthreads();

    // rank into staging (loff doubles as cursor)
#pragma unroll
    for (int i = 0; i < EPT; ++i) {
        if (myb[i] >= 0) {
            int pos = atomicAdd(&loff[myb[i]], 1);
            vals[pos] = myval[i];
            buks[pos] = (ushort_t)myb[i];
        }
    }
    __syncthreads();

    // linear write-out: consecutive i -> consecutive gaddr within each run
    for (int i = t; i < cnt; i += 512)
        ebuf[hist[buks[i]] + i] = vals[i];
}

// ---------------- device body: per-bucket degrees/offsets/slice-sorted csr ----------------
// smem: hist [0,8192) 2048 ints ((node,slice) counts then cursors); lds8 [8192,8224)
__device__ void dev_bucket_csr(const uint_t* __restrict__ ebuf, const int* __restrict__ bkt_cnt,
                               int N, int* __restrict__ deg, int* __restrict__ off,
                               int* __restrict__ csr, char* smem, int b) {
    int* hist = (int*)smem;
    int* lds8 = (int*)(smem + 8192);
    int t = threadIdx.x;
    int beg = b << CAPLOG;
    int end = beg + bkt_cnt[b];
    for (int i = t; i < 256 * NSLICE; i += 512) hist[i] = 0;
    __syncthreads();
    for (int j = beg + t; j < end; j += 512) {
        uint_t v = ebuf[j];
        int key = ((v & 255u) << 3) | ((v >> 8) / SLDIV);
        atomicAdd(&hist[key], 1);
    }
    __syncthreads();
    // deg (pure reads)
    if (t < 256) {
        int node = (b << 8) + t;
        if (node < N) {
            int s = 0;
#pragma unroll
            for (int i = 0; i < NSLICE; ++i) s += hist[(t << 3) | i];
            deg[node] = s;
        }
    }
    // scan of 2048: thread t owns hist[4t..4t+3]; all reads precede the
    // exscan512 barrier, all cursor writes follow it.
    int c0 = hist[4 * t], c1 = hist[4 * t + 1], c2 = hist[4 * t + 2], c3 = hist[4 * t + 3];
    int s4 = c0 + c1 + c2 + c3;
    int base = beg + exscan512(s4, lds8, t);
    hist[4 * t]     = base;
    hist[4 * t + 1] = base + c0;
    hist[4 * t + 2] = base + c0 + c1;
    hist[4 * t + 3] = base + c0 + c1 + c2;
    __syncthreads();
    if (t < 256) {
        int node = (b << 8) + t;
        if (node < N) off[node] = hist[t << 3];
    }
    __syncthreads();
    for (int j = beg + t; j < end; j += 512) {
        uint_t v = ebuf[j];
        int key = ((v & 255u) << 3) | ((v >> 8) / SLDIV);
        int pos = atomicAdd(&hist[key], 1);
        csr[pos] = (int)(v >> 8);
    }
}

// ---------------- device body: layer1 GEMM (512-thread variant, 128 nodes/block) ----------------
// h^T = W^T . x^T per mfma_f32_16x16x32_bf16 tile. NO LDS: A-fragments from
// global bf16 Wt[64][256] (32KB, L1/L2 resident).
__device__ void dev_gemm1(const float* __restrict__ x, const ushort_t* __restrict__ Wtg,
                          const float* __restrict__ att_s, const float* __restrict__ att_d,
                          ushort_t* __restrict__ h1b, ushort_t* __restrict__ as1b,
                          float* __restrict__ ad1, int N, int nodeBase512) {
    const int t = threadIdx.x;
    const int wv = t >> 6, l = t & 63;
    const int l15 = l & 15, q = l >> 4;
    const int node = nodeBase512 + wv * 16 + l15;
    const bool ok = node < N;
    const float* xr = x + (size_t)(ok ? node : N - 1) * FIN;

    f32x4 acc[4];   // [ct] : output channels ct*16 + q*4 + 0..3, col = node
#pragma unroll
    for (int ct = 0; ct < 4; ++ct) acc[ct] = (f32x4){0.f, 0.f, 0.f, 0.f};

    for (int kk = 0; kk < 8; ++kk) {
        const int kof = kk * 32 + q * 8;
        short8 af[4];
#pragma unroll
        for (int ct = 0; ct < 4; ++ct)
            af[ct] = *reinterpret_cast<const short8*>(&Wtg[(ct * 16 + l15) * 256 + kof]);
        const float4* xp = reinterpret_cast<const float4*>(xr + kof);
        float4 v0 = xp[0], v1 = xp[1];
        union { short8 s; uint_t u[4]; } bu;
        bu.u[0] = packbf2(v0.x, v0.y);
        bu.u[1] = packbf2(v0.z, v0.w);
        bu.u[2] = packbf2(v1.x, v1.y);
        bu.u[3] = packbf2(v1.z, v1.w);
#pragma unroll
        for (int ct = 0; ct < 4; ++ct)
            acc[ct] = __builtin_amdgcn_mfma_f32_16x16x32_bf16(af[ct], bu.s, acc[ct], 0, 0, 0);
    }

    float4 ats[4], atd4[4];
#pragma unroll
    for (int ct = 0; ct < 4; ++ct) {
        ats[ct]  = *reinterpret_cast<const float4*>(&att_s[ct * 16 + q * 4]);
        atd4[ct] = *reinterpret_cast<const float4*>(&att_d[ct * 16 + q * 4]);
    }
    const int hb = q >> 1;

    float asp[8], adp[8];
#pragma unroll
    for (int h = 0; h < 8; ++h) { asp[h] = 0.f; adp[h] = 0.f; }
#pragma unroll
    for (int ct = 0; ct < 4; ++ct) {
        f32x4 a = acc[ct];
        if (ok) {
            uint2 hv;
            hv.x = packbf2(a[0], a[1]);
            hv.y = packbf2(a[2], a[3]);
            *reinterpret_cast<uint2*>(&h1b[(size_t)node * C1 + ct * 16 + q * 4]) = hv;
        }
        int h = ct * 2 + hb;
        asp[h] = a[0] * ats[ct].x + a[1] * ats[ct].y + a[2] * ats[ct].z + a[3] * ats[ct].w;
        adp[h] = a[0] * atd4[ct].x + a[1] * atd4[ct].y + a[2] * atd4[ct].z + a[3] * atd4[ct].w;
    }
#pragma unroll
    for (int o = 16; o <= 32; o <<= 1) {
#pragma unroll
        for (int h = 0; h < 8; ++h) {
            asp[h] += __shfl_xor(asp[h], o, 64);
            adp[h] += __shfl_xor(adp[h], o, 64);
        }
    }
    if (q == 0 && ok) {
        uint4 aw;
        aw.x = packbf2(asp[0], asp[1]);
        aw.y = packbf2(asp[2], asp[3]);
        aw.z = packbf2(asp[4], asp[5]);
        aw.w = packbf2(asp[6], asp[7]);
        *reinterpret_cast<uint4*>(&as1b[(size_t)node * NH]) = aw;
        *reinterpret_cast<float4*>(&ad1[(size_t)node * NH]) =
            make_float4(adp[0], adp[1], adp[2], adp[3]);
        *reinterpret_cast<float4*>(&ad1[(size_t)node * NH + 4]) =
            make_float4(adp[4], adp[5], adp[6], adp[7]);
    }
}

// ---------------- fat kernel A: bscatter ++ gemm1(first node half) ----------------
__global__ __launch_bounds__(512) void k_fatA(
    const int* __restrict__ ei, int E, int N, int NBUK, int* __restrict__ bkt_cnt,
    uint_t* __restrict__ ebuf,
    const float* __restrict__ x, const ushort_t* __restrict__ Wtg,
    const float* __restrict__ ats, const float* __restrict__ atd,
    ushort_t* __restrict__ h1b, ushort_t* __restrict__ as1b, float* __restrict__ ad1,
    int nbsc)
{
    __shared__ __align__(16) char smem[53312];
    if ((int)blockIdx.x < nbsc)
        dev_bscatter(ei, E, N, NBUK, bkt_cnt, ebuf, smem, blockIdx.x);
    else
        dev_gemm1(x, Wtg, ats, atd, h1b, as1b, ad1, N, ((int)blockIdx.x - nbsc) * 128);
}

// ---------------- fat kernel B: bucket_csr ++ gemm1(second node half) ----------------
__global__ __launch_bounds__(512) void k_fatB(
    const uint_t* __restrict__ ebuf, const int* __restrict__ bkt_cnt, int N,
    int* __restrict__ deg, int* __restrict__ off, int* __restrict__ csr,
    const float* __restrict__ x, const ushort_t* __restrict__ Wtg,
    const float* __restrict__ ats, const float* __restrict__ atd,
    ushort_t* __restrict__ h1b, ushort_t* __restrict__ as1b, float* __restrict__ ad1,
    int nbuk, int nodeOfs)
{
    __shared__ __align__(16) char smem[8256];
    if ((int)blockIdx.x < nbuk)
        dev_bucket_csr(ebuf, bkt_cnt, N, deg, off, csr, smem, blockIdx.x);
    else
        dev_gemm1(x, Wtg, ats, atd, h1b, as1b, ad1, N,
                  nodeOfs + ((int)blockIdx.x - nbuk) * 128);
}

// ---------------- fused layer1 aggregation + bias/ELU + W2 projection ----------------
// R2 verbatim. 4 nodes per wave, 16 lanes/node: sub = lane&15, slot = sub>>2,
// hp = sub&3. csr is slice-sorted (8 src slices), so the stride-4 slot loop
// sweeps src slices monotonically per node -> smaller L2 working set.
__global__ __launch_bounds__(256) void k_agg1(
    const int* __restrict__ csr, const int* __restrict__ off, const int* __restrict__ deg,
    const ushort_t* __restrict__ as1b, const float* __restrict__ ad1,
    const ushort_t* __restrict__ h1b,
    const float* __restrict__ b1, const float* __restrict__ W2,
    float* __restrict__ h2, int N)
{
    int idx = blockIdx.x * 256 + threadIdx.x;
    int n = idx >> 4;
    if (n >= N) return;
    int sub  = threadIdx.x & 15;
    int hp   = sub & 3;
    int slot = sub >> 2;

    int beg = off[n];
    int end = beg + deg[n];

    float adv0 = ad1[(size_t)n * NH + 2 * hp];
    float adv1 = ad1[(size_t)n * NH + 2 * hp + 1];
    float den0 = 0.f, den1 = 0.f;
    float acc[16];
#pragma unroll
    for (int k = 0; k < 16; ++k) acc[k] = 0.f;

    for (int base = beg; base < end; base += 4) {
        int j = base + slot;
        int jj = j < end ? j : end - 1;
        int s = csr[jj];
        uint_t a2 = *reinterpret_cast<const uint_t*>(&as1b[(size_t)s * NH + 2 * hp]);
        float t0 = bf_lo(a2) + adv0;
        float t1 = bf_hi(a2) + adv1;
        t0 = fmaxf(t0, 0.2f * t0);
        t1 = fmaxf(t1, 0.2f * t1);
        bool live = j < end;
        float ex0 = live ? __expf(t0) : 0.f;
        float ex1 = live ? __expf(t1) : 0.f;
        den0 += ex0; den1 += ex1;
        const uint4* hbp = reinterpret_cast<const uint4*>(&h1b[(size_t)s * C1 + hp * 16]);
        uint4 u0 = hbp[0], u1 = hbp[1];
        acc[0]  = fmaf(ex0, bf_lo(u0.x), acc[0]);
        acc[1]  = fmaf(ex0, bf_hi(u0.x), acc[1]);
        acc[2]  = fmaf(ex0, bf_lo(u0.y), acc[2]);
        acc[3]  = fmaf(ex0, bf_hi(u0.y), acc[3]);
        acc[4]  = fmaf(ex0, bf_lo(u0.z), acc[4]);
        acc[5]  = fmaf(ex0, bf_hi(u0.z), acc[5]);
        acc[6]  = fmaf(ex0, bf_lo(u0.w), acc[6]);
        acc[7]  = fmaf(ex0, bf_hi(u0.w), acc[7]);
        acc[8]  = fmaf(ex1, bf_lo(u1.x), acc[8]);
        acc[9]  = fmaf(ex1, bf_hi(u1.x), acc[9]);
        acc[10] = fmaf(ex1, bf_lo(u1.y), acc[10]);
        acc[11] = fmaf(ex1, bf_hi(u1.y), acc[11]);
        acc[12] = fmaf(ex1, bf_lo(u1.z), acc[12]);
        acc[13] = fmaf(ex1, bf_hi(u1.z), acc[13]);
        acc[14] = fmaf(ex1, bf_lo(u1.w), acc[14]);
        acc[15] = fmaf(ex1, bf_hi(u1.w), acc[15]);
    }

#pragma unroll
    for (int o = 4; o <= 8; o <<= 1) {
        den0 += __shfl_xor(den0, o, 64);
        den1 += __shfl_xor(den1, o, 64);
#pragma unroll
        for (int k = 0; k < 16; ++k) acc[k] += __shfl_xor(acc[k], o, 64);
    }

    float inv0 = 1.f / (den0 + 1e-16f);
    float inv1 = 1.f / (den1 + 1e-16f);
    const float4* bp = reinterpret_cast<const float4*>(&b1[hp * 16]);
    const float4* wp = reinterpret_cast<const float4*>(&W2[hp * 16]);
    float bb[16], ww[16];
#pragma unroll
    for (int i = 0; i < 4; ++i) {
        float4 b4 = bp[i], w4 = wp[i];
        bb[4 * i] = b4.x; bb[4 * i + 1] = b4.y; bb[4 * i + 2] = b4.z; bb[4 * i + 3] = b4.w;
        ww[4 * i] = w4.x; ww[4 * i + 1] = w4.y; ww[4 * i + 2] = w4.z; ww[4 * i + 3] = w4.w;
    }
    float p = 0.f;
#pragma unroll
    for (int k = 0; k < 16; ++k) {
        float inv = (k < 8) ? inv0 : inv1;
        float v = acc[k] * inv + bb[k];
        v = v > 0.f ? v : (__expf(v) - 1.f);  // ELU, fast path
        p = fmaf(v, ww[k], p);
    }
#pragma unroll
    for (int o = 1; o <= 2; o <<= 1) p += __shfl_xor(p, o, 64);
    if (sub == 0) h2[n] = p;
}

// ---------------- fused layer2: softmax + aggregate + bias + sigmoid ----------------
__global__ __launch_bounds__(256) void k_agg2(
    const int* __restrict__ csr, const int* __restrict__ off, const int* __restrict__ deg,
    const float* __restrict__ h2,
    const float* __restrict__ ats2, const float* __restrict__ atd2,
    const float* __restrict__ b2, float* __restrict__ out, int N)
{
    int idx = blockIdx.x * 256 + threadIdx.x;
    int n = idx >> 4;
    int l16 = threadIdx.x & 15;
    if (n >= N) return;
    int beg = off[n];
    int end = beg + deg[n];
    float a_s = ats2[0], a_d = atd2[0];
    float adv = h2[n] * a_d;
    float den = 0.f, num = 0.f;
    for (int j = beg + l16; j < end; j += 16) {
        float hs = h2[csr[j]];
        float t = fmaf(hs, a_s, adv);
        t = fmaxf(t, 0.2f * t);
        float ex = __expf(t);
        den += ex;
        num = fmaf(ex, hs, num);
    }
#pragma unroll
    for (int o = 1; o <= 8; o <<= 1) {
        den += __shfl_xor(den, o, 64);
        num += __shfl_xor(num, o, 64);
    }
    if (l16 == 0) {
        float t = num / (den + 1e-16f) + b2[0];
        out[n] = 1.f / (1.f + __expf(-t));
    }
}

extern "C" void kernel_launch(void* const* d_in, const int* in_sizes, int n_in,
                              void* d_out, int out_size, void* d_ws, size_t ws_size,
                              hipStream_t stream)
{
    const float* x    = (const float*)d_in[0];
    const int*   ei   = (const int*)d_in[1];
    const float* W1   = (const float*)d_in[2];
    const float* ats1 = (const float*)d_in[3];
    const float* atd1 = (const float*)d_in[4];
    const float* b1   = (const float*)d_in[5];
    const float* W2   = (const float*)d_in[6];
    const float* ats2 = (const float*)d_in[7];
    const float* atd2 = (const float*)d_in[8];
    const float* b2   = (const float*)d_in[9];
    float* out = (float*)d_out;

    const int N = out_size;            // 100000
    const int E = in_sizes[1] / 2;     // 3200000
    const int Etot = E + N;
    const int NBUK = (N + 255) >> 8;   // 391 (<= MAXBUK)
    const size_t capElems = (size_t)NBUK << CAPLOG;   // 6.4M slots (25.6 MB)

    // workspace layout:
    //   union region: ebuf uint[NBUK<<CAPLOG] (25.6MB)  OVERLAYS  feature block
    //                 {h1b bf16[N*64], as1b bf16[N*8], ad1 f32[N*8], h2 f32[N]} (18MB)
    //   then ints: deg[N] off[N] bkt_cnt[512] csr[capElems]  then Wt bf16[64*256]
    //   NOTE: fatA writes ebuf while gemm1-half writes h1b/as1b/ad1 -> they must
    //   NOT overlap anymore. Feature block moved AFTER ebuf (no union).
    char* base = (char*)d_ws;
    uint_t* ebuf = (uint_t*)base;
    size_t ebufBytes = (capElems * sizeof(uint_t) + 255) & ~(size_t)255;
    ushort_t* h1b  = (ushort_t*)(base + ebufBytes);
    ushort_t* as1b = h1b + (size_t)N * C1;
    float* ad1 = (float*)(as1b + (size_t)N * NH);
    float* h2  = ad1 + (size_t)N * NH;
    char* pend = (char*)(h2 + N);
    size_t featEnd = ((size_t)(pend - base) + 255) & ~(size_t)255;
    int* deg     = (int*)(base + featEnd);
    int* off     = deg + N;
    int* bkt_cnt = off + N;
    int* csr     = bkt_cnt + MAXBUK;
    ushort_t* wtg = (ushort_t*)(csr + capElems);   // 32 KB global Wt

    const int nbsc = (Etot + SC_CHUNK - 1) / SC_CHUNK;     // 403
    const int halfNodes = (((N / 2) + 127) / 128) * 128;   // 50048
    const int ga = halfNodes / 128;                        // 391 gemm blocks (first half)
    const int gb = (N - halfNodes + 127) / 128;            // 391 gemm blocks (second half)

    k_prep<<<64, 256, 0, stream>>>(W1, wtg, bkt_cnt);
    k_fatA<<<nbsc + ga, 512, 0, stream>>>(ei, E, N, NBUK, bkt_cnt, ebuf,
                                          x, wtg, ats1, atd1, h1b, as1b, ad1, nbsc);
    k_fatB<<<NBUK + gb, 512, 0, stream>>>(ebuf, bkt_cnt, N, deg, off, csr,
                                          x, wtg, ats1, atd1, h1b, as1b, ad1,
                                          NBUK, halfNodes);
    k_agg1<<<(N * 16 + 255) / 256, 256, 0, stream>>>(csr, off, deg, as1b, ad1, h1b, b1, W2, h2, N);
    k_agg2<<<(N * 16 + 255) / 256, 256, 0, stream>>>(csr, off, deg, h2, ats2, atd2, b2, out, N);
}

// Round 8
// 328.098 us; speedup vs baseline: 1.1086x; 1.0023x over previous
//
#include <hip/hip_runtime.h>
#include <math.h>

// GAT 2-layer pipeline. CSR-by-dst built per launch via LDS-staged counting
// sort into FIXED-CAPACITY buckets (16384 slots/bucket). Aggregation:
// atomic-free per-node online softmax, bf16 features (absmax ~4e-3 << 1.1e-2
// threshold). Layer-1 GEMM on MFMA (bf16): h^T = W^T . x^T.
// Sizes fixed by reference: F_IN=256, HEADS=8, HID=8 -> C1=64; layer2 1x1.
//
// R8: agg1 MLP probe. Evidence agg1 is partially LATENCY-bound, not purely
// BW-bound: R5/R6 cut traffic 14% (224->193MB) but time fell only 8.6% and
// the effective rate DROPPED 3.07->2.85 TB/s (a BW-bound kernel holds rate
// constant); VALUBusy 47%, VGPR=32 (no compiler pipelining of the dependent
// csr->gather->FMA chain; only 4 edges in flight per node). Fix: manual 2x
// unroll of the edge loop - issue both csr loads + both as-gathers + all 4
// h1 uint4 loads before consuming -> 8 edges in flight. Same arithmetic
// order per lane (edge base+4 was the next iteration), bit-identical result.
// Pre-commit: if agg1 within +-2us of 67.8, it IS BW-bound -> structural floor.
// (R7 fat-kernel overlap kept: neutral, harmless.)
#define FIN 256
#define C1  64
#define NH  8
#define HID 8
#define MAXBUK 512        // buckets of 256 nodes; N=100000 -> 391 buckets
#define CAPLOG 14         // fixed bucket capacity 16384 edges
#define SC_CHUNK 8192     // edges per bscatter block (512 thr, EPT 16)
#define EPT (SC_CHUNK / 512)
#define NSLICE 8          // src slices for csr ordering (agg1 L2 phasing)
#define SLDIV 12500u      // slice = src / SLDIV (N=100000 -> 8 even slices)

typedef unsigned short ushort_t;
typedef unsigned int uint_t;
typedef __attribute__((ext_vector_type(8))) short short8;   // 8 x bf16 MFMA frag
typedef __attribute__((ext_vector_type(4))) float f32x4;    // MFMA acc

__device__ __forceinline__ ushort_t f2bf(float f) {   // round-to-nearest-even
    uint_t u = __float_as_uint(f);
    u += 0x7fffu + ((u >> 16) & 1u);
    return (ushort_t)(u >> 16);
}
__device__ __forceinline__ uint_t packbf2(float lo, float hi) {
    return (uint_t)f2bf(lo) | ((uint_t)f2bf(hi) << 16);
}
__device__ __forceinline__ float bf_lo(uint_t w) { return __uint_as_float(w << 16); }
__device__ __forceinline__ float bf_hi(uint_t w) { return __uint_as_float(w & 0xffff0000u); }

// block-wide (512 thr) exclusive scan: shfl wave-scan + 8-entry LDS fixup.
__device__ __forceinline__ int exscan512(int v, int* lds8, int t) {
    int lane = t & 63, w = t >> 6;
    int sc = v;
#pragma unroll
    for (int o = 1; o < 64; o <<= 1) {
        int u = __shfl_up(sc, o, 64);
        if (lane >= o) sc += u;
    }
    if (lane == 63) lds8[w] = sc;
    __syncthreads();
    int woff = 0;
#pragma unroll
    for (int i = 0; i < 8; ++i) woff += (i < w) ? lds8[i] : 0;
    return woff + sc - v;
}

// ---------------- prep: zero bkt_cnt + transpose W -> global bf16 Wt[64][256] ----------------
__global__ void k_prep(const float* __restrict__ W, ushort_t* __restrict__ Wtg,
                       int* __restrict__ bkt_cnt) {
    int tid = blockIdx.x * 256 + threadIdx.x;
    if (tid < MAXBUK) bkt_cnt[tid] = 0;
    int c = tid >> 8;        // 0..63
    int k = tid & 255;       // 0..255
    Wtg[c * 256 + k] = f2bf(W[k * C1 + c]);
}

// ---------------- device body: bucket scatter (one 8192-edge chunk) ----------------
__device__ void dev_bscatter(const int* __restrict__ ei, int E, int N, int NBUK,
                             int* __restrict__ bkt_cnt, uint_t* __restrict__ ebuf,
                             char* smem, int bid) {
    int* hist = (int*)smem;
    int* loff = (int*)(smem + 2048);
    int* lds8 = (int*)(smem + 4096);
    uint_t* vals = (uint_t*)(smem + 4160);
    ushort_t* buks = (ushort_t*)(smem + 36928);

    const int t = threadIdx.x;
    hist[t] = 0;
    __syncthreads();

    const int Etot = E + N;
    const int base0 = bid * SC_CHUNK;
    const int lim = min(base0 + SC_CHUNK, Etot);
    const int cnt = lim - base0;

    uint_t myval[EPT];
    int myb[EPT];
#pragma unroll
    for (int i = 0; i < EPT; ++i) {
        int e = base0 + t + i * 512;
        if (e < lim) {
            int s, d;
            if (e < E) { s = ei[e]; d = ei[E + e]; } else { s = e - E; d = s; }
            myval[i] = ((uint_t)s << 8) | (uint_t)(d & 255);
            myb[i] = d >> 8;
            atomicAdd(&hist[myb[i]], 1);
        } else myb[i] = -1;
    }
    __syncthreads();

    int v = hist[t];
    int ex = exscan512(v, lds8, t);
    loff[t] = ex;
    __syncthreads();

    if (t < NBUK) {
        int c = hist[t];
        if (c) hist[t] = (t << CAPLOG) + atomicAdd(&bkt_cnt[t], c) - ex;
    }
    __syncthreads();

#pragma unroll
    for (int i = 0; i < EPT; ++i) {
        if (myb[i] >= 0) {
            int pos = atomicAdd(&loff[myb[i]], 1);
            vals[pos] = myval[i];
            buks[pos] = (ushort_t)myb[i];
        }
    }
    __syncthreads();

    for (int i = t; i < cnt; i += 512)
        ebuf[hist[buks[i]] + i] = vals[i];
}

// ---------------- device body: per-bucket degrees/offsets/slice-sorted csr ----------------
__device__ void dev_bucket_csr(const uint_t* __restrict__ ebuf, const int* __restrict__ bkt_cnt,
                               int N, int* __restrict__ deg, int* __restrict__ off,
                               int* __restrict__ csr, char* smem, int b) {
    int* hist = (int*)smem;
    int* lds8 = (int*)(smem + 8192);
    int t = threadIdx.x;
    int beg = b << CAPLOG;
    int end = beg + bkt_cnt[b];
    for (int i = t; i < 256 * NSLICE; i += 512) hist[i] = 0;
    __syncthreads();
    for (int j = beg + t; j < end; j += 512) {
        uint_t v = ebuf[j];
        int key = ((v & 255u) << 3) | ((v >> 8) / SLDIV);
        atomicAdd(&hist[key], 1);
    }
    __syncthreads();
    if (t < 256) {
        int node = (b << 8) + t;
        if (node < N) {
            int s = 0;
#pragma unroll
            for (int i = 0; i < NSLICE; ++i) s += hist[(t << 3) | i];
            deg[node] = s;
        }
    }
    int c0 = hist[4 * t], c1 = hist[4 * t + 1], c2 = hist[4 * t + 2], c3 = hist[4 * t + 3];
    int s4 = c0 + c1 + c2 + c3;
    int base = beg + exscan512(s4, lds8, t);
    hist[4 * t]     = base;
    hist[4 * t + 1] = base + c0;
    hist[4 * t + 2] = base + c0 + c1;
    hist[4 * t + 3] = base + c0 + c1 + c2;
    __syncthreads();
    if (t < 256) {
        int node = (b << 8) + t;
        if (node < N) off[node] = hist[t << 3];
    }
    __syncthreads();
    for (int j = beg + t; j < end; j += 512) {
        uint_t v = ebuf[j];
        int key = ((v & 255u) << 3) | ((v >> 8) / SLDIV);
        int pos = atomicAdd(&hist[key], 1);
        csr[pos] = (int)(v >> 8);
    }
}

// ---------------- device body: layer1 GEMM (512-thread variant, 128 nodes/block) ----------------
__device__ void dev_gemm1(const float* __restrict__ x, const ushort_t* __restrict__ Wtg,
                          const float* __restrict__ att_s, const float* __restrict__ att_d,
                          ushort_t* __restrict__ h1b, ushort_t* __restrict__ as1b,
                          float* __restrict__ ad1, int N, int nodeBase512) {
    const int t = threadIdx.x;
    const int wv = t >> 6, l = t & 63;
    const int l15 = l & 15, q = l >> 4;
    const int node = nodeBase512 + wv * 16 + l15;
    const bool ok = node < N;
    const float* xr = x + (size_t)(ok ? node : N - 1) * FIN;

    f32x4 acc[4];
#pragma unroll
    for (int ct = 0; ct < 4; ++ct) acc[ct] = (f32x4){0.f, 0.f, 0.f, 0.f};

    for (int kk = 0; kk < 8; ++kk) {
        const int kof = kk * 32 + q * 8;
        short8 af[4];
#pragma unroll
        for (int ct = 0; ct < 4; ++ct)
            af[ct] = *reinterpret_cast<const short8*>(&Wtg[(ct * 16 + l15) * 256 + kof]);
        const float4* xp = reinterpret_cast<const float4*>(xr + kof);
        float4 v0 = xp[0], v1 = xp[1];
        union { short8 s; uint_t u[4]; } bu;
        bu.u[0] = packbf2(v0.x, v0.y);
        bu.u[1] = packbf2(v0.z, v0.w);
        bu.u[2] = packbf2(v1.x, v1.y);
        bu.u[3] = packbf2(v1.z, v1.w);
#pragma unroll
        for (int ct = 0; ct < 4; ++ct)
            acc[ct] = __builtin_amdgcn_mfma_f32_16x16x32_bf16(af[ct], bu.s, acc[ct], 0, 0, 0);
    }

    float4 ats[4], atd4[4];
#pragma unroll
    for (int ct = 0; ct < 4; ++ct) {
        ats[ct]  = *reinterpret_cast<const float4*>(&att_s[ct * 16 + q * 4]);
        atd4[ct] = *reinterpret_cast<const float4*>(&att_d[ct * 16 + q * 4]);
    }
    const int hb = q >> 1;

    float asp[8], adp[8];
#pragma unroll
    for (int h = 0; h < 8; ++h) { asp[h] = 0.f; adp[h] = 0.f; }
#pragma unroll
    for (int ct = 0; ct < 4; ++ct) {
        f32x4 a = acc[ct];
        if (ok) {
            uint2 hv;
            hv.x = packbf2(a[0], a[1]);
            hv.y = packbf2(a[2], a[3]);
            *reinterpret_cast<uint2*>(&h1b[(size_t)node * C1 + ct * 16 + q * 4]) = hv;
        }
        int h = ct * 2 + hb;
        asp[h] = a[0] * ats[ct].x + a[1] * ats[ct].y + a[2] * ats[ct].z + a[3] * ats[ct].w;
        adp[h] = a[0] * atd4[ct].x + a[1] * atd4[ct].y + a[2] * atd4[ct].z + a[3] * atd4[ct].w;
    }
#pragma unroll
    for (int o = 16; o <= 32; o <<= 1) {
#pragma unroll
        for (int h = 0; h < 8; ++h) {
            asp[h] += __shfl_xor(asp[h], o, 64);
            adp[h] += __shfl_xor(adp[h], o, 64);
        }
    }
    if (q == 0 && ok) {
        uint4 aw;
        aw.x = packbf2(asp[0], asp[1]);
        aw.y = packbf2(asp[2], asp[3]);
        aw.z = packbf2(asp[4], asp[5]);
        aw.w = packbf2(asp[6], asp[7]);
        *reinterpret_cast<uint4*>(&as1b[(size_t)node * NH]) = aw;
        *reinterpret_cast<float4*>(&ad1[(size_t)node * NH]) =
            make_float4(adp[0], adp[1], adp[2], adp[3]);
        *reinterpret_cast<float4*>(&ad1[(size_t)node * NH + 4]) =
            make_float4(adp[4], adp[5], adp[6], adp[7]);
    }
}

// ---------------- fat kernel A: bscatter ++ gemm1(first node half) ----------------
__global__ __launch_bounds__(512) void k_fatA(
    const int* __restrict__ ei, int E, int N, int NBUK, int* __restrict__ bkt_cnt,
    uint_t* __restrict__ ebuf,
    const float* __restrict__ x, const ushort_t* __restrict__ Wtg,
    const float* __restrict__ ats, const float* __restrict__ atd,
    ushort_t* __restrict__ h1b, ushort_t* __restrict__ as1b, float* __restrict__ ad1,
    int nbsc)
{
    __shared__ __align__(16) char smem[53312];
    if ((int)blockIdx.x < nbsc)
        dev_bscatter(ei, E, N, NBUK, bkt_cnt, ebuf, smem, blockIdx.x);
    else
        dev_gemm1(x, Wtg, ats, atd, h1b, as1b, ad1, N, ((int)blockIdx.x - nbsc) * 128);
}

// ---------------- fat kernel B: bucket_csr ++ gemm1(second node half) ----------------
__global__ __launch_bounds__(512) void k_fatB(
    const uint_t* __restrict__ ebuf, const int* __restrict__ bkt_cnt, int N,
    int* __restrict__ deg, int* __restrict__ off, int* __restrict__ csr,
    const float* __restrict__ x, const ushort_t* __restrict__ Wtg,
    const float* __restrict__ ats, const float* __restrict__ atd,
    ushort_t* __restrict__ h1b, ushort_t* __restrict__ as1b, float* __restrict__ ad1,
    int nbuk, int nodeOfs)
{
    __shared__ __align__(16) char smem[8256];
    if ((int)blockIdx.x < nbuk)
        dev_bucket_csr(ebuf, bkt_cnt, N, deg, off, csr, smem, blockIdx.x);
    else
        dev_gemm1(x, Wtg, ats, atd, h1b, as1b, ad1, N,
                  nodeOfs + ((int)blockIdx.x - nbuk) * 128);
}

// ---------------- fused layer1 aggregation + bias/ELU + W2 projection ----------------
// 4 nodes per wave, 16 lanes/node: sub = lane&15, slot = sub>>2, hp = sub&3.
// Edge loop 2x unrolled: 8 edges in flight per node (MLP for the dependent
// csr->gather chain). Same per-lane arithmetic order as the stride-4 loop.
__global__ __launch_bounds__(256) void k_agg1(
    const int* __restrict__ csr, const int* __restrict__ off, const int* __restrict__ deg,
    const ushort_t* __restrict__ as1b, const float* __restrict__ ad1,
    const ushort_t* __restrict__ h1b,
    const float* __restrict__ b1, const float* __restrict__ W2,
    float* __restrict__ h2, int N)
{
    int idx = blockIdx.x * 256 + threadIdx.x;
    int n = idx >> 4;
    if (n >= N) return;
    int sub  = threadIdx.x & 15;
    int hp   = sub & 3;
    int slot = sub >> 2;

    int beg = off[n];
    int end = beg + deg[n];

    float adv0 = ad1[(size_t)n * NH + 2 * hp];
    float adv1 = ad1[(size_t)n * NH + 2 * hp + 1];
    float den0 = 0.f, den1 = 0.f;
    float acc[16];
#pragma unroll
    for (int k = 0; k < 16; ++k) acc[k] = 0.f;

    for (int base = beg; base < end; base += 8) {
        int ja = base + slot;
        int jb = base + 4 + slot;
        int jja = ja < end ? ja : end - 1;
        int jjb = jb < end ? jb : end - 1;
        int sa = csr[jja];
        int sb = csr[jjb];
        uint_t a2a = *reinterpret_cast<const uint_t*>(&as1b[(size_t)sa * NH + 2 * hp]);
        uint_t a2b = *reinterpret_cast<const uint_t*>(&as1b[(size_t)sb * NH + 2 * hp]);
        const uint4* hpa = reinterpret_cast<const uint4*>(&h1b[(size_t)sa * C1 + hp * 16]);
        const uint4* hpb = reinterpret_cast<const uint4*>(&h1b[(size_t)sb * C1 + hp * 16]);
        uint4 ua0 = hpa[0], ua1 = hpa[1];
        uint4 ub0 = hpb[0], ub1 = hpb[1];

        float ta0 = bf_lo(a2a) + adv0;
        float ta1 = bf_hi(a2a) + adv1;
        ta0 = fmaxf(ta0, 0.2f * ta0);
        ta1 = fmaxf(ta1, 0.2f * ta1);
        bool livea = ja < end;
        float exa0 = livea ? __expf(ta0) : 0.f;
        float exa1 = livea ? __expf(ta1) : 0.f;
        float tb0 = bf_lo(a2b) + adv0;
        float tb1 = bf_hi(a2b) + adv1;
        tb0 = fmaxf(tb0, 0.2f * tb0);
        tb1 = fmaxf(tb1, 0.2f * tb1);
        bool liveb = jb < end;
        float exb0 = liveb ? __expf(tb0) : 0.f;
        float exb1 = liveb ? __expf(tb1) : 0.f;

        den0 += exa0; den1 += exa1;
        acc[0]  = fmaf(exa0, bf_lo(ua0.x), acc[0]);
        acc[1]  = fmaf(exa0, bf_hi(ua0.x), acc[1]);
        acc[2]  = fmaf(exa0, bf_lo(ua0.y), acc[2]);
        acc[3]  = fmaf(exa0, bf_hi(ua0.y), acc[3]);
        acc[4]  = fmaf(exa0, bf_lo(ua0.z), acc[4]);
        acc[5]  = fmaf(exa0, bf_hi(ua0.z), acc[5]);
        acc[6]  = fmaf(exa0, bf_lo(ua0.w), acc[6]);
        acc[7]  = fmaf(exa0, bf_hi(ua0.w), acc[7]);
        acc[8]  = fmaf(exa1, bf_lo(ua1.x), acc[8]);
        acc[9]  = fmaf(exa1, bf_hi(ua1.x), acc[9]);
        acc[10] = fmaf(exa1, bf_lo(ua1.y), acc[10]);
        acc[11] = fmaf(exa1, bf_hi(ua1.y), acc[11]);
        acc[12] = fmaf(exa1, bf_lo(ua1.z), acc[12]);
        acc[13] = fmaf(exa1, bf_hi(ua1.z), acc[13]);
        acc[14] = fmaf(exa1, bf_lo(ua1.w), acc[14]);
        acc[15] = fmaf(exa1, bf_hi(ua1.w), acc[15]);

        den0 += exb0; den1 += exb1;
        acc[0]  = fmaf(exb0, bf_lo(ub0.x), acc[0]);
        acc[1]  = fmaf(exb0, bf_hi(ub0.x), acc[1]);
        acc[2]  = fmaf(exb0, bf_lo(ub0.y), acc[2]);
        acc[3]  = fmaf(exb0, bf_hi(ub0.y), acc[3]);
        acc[4]  = fmaf(exb0, bf_lo(ub0.z), acc[4]);
        acc[5]  = fmaf(exb0, bf_hi(ub0.z), acc[5]);
        acc[6]  = fmaf(exb0, bf_lo(ub0.w), acc[6]);
        acc[7]  = fmaf(exb0, bf_hi(ub0.w), acc[7]);
        acc[8]  = fmaf(exb1, bf_lo(ub1.x), acc[8]);
        acc[9]  = fmaf(exb1, bf_hi(ub1.x), acc[9]);
        acc[10] = fmaf(exb1, bf_lo(ub1.y), acc[10]);
        acc[11] = fmaf(exb1, bf_hi(ub1.y), acc[11]);
        acc[12] = fmaf(exb1, bf_lo(ub1.z), acc[12]);
        acc[13] = fmaf(exb1, bf_hi(ub1.z), acc[13]);
        acc[14] = fmaf(exb1, bf_lo(ub1.w), acc[14]);
        acc[15] = fmaf(exb1, bf_hi(ub1.w), acc[15]);
    }

#pragma unroll
    for (int o = 4; o <= 8; o <<= 1) {
        den0 += __shfl_xor(den0, o, 64);
        den1 += __shfl_xor(den1, o, 64);
#pragma unroll
        for (int k = 0; k < 16; ++k) acc[k] += __shfl_xor(acc[k], o, 64);
    }

    float inv0 = 1.f / (den0 + 1e-16f);
    float inv1 = 1.f / (den1 + 1e-16f);
    const float4* bp = reinterpret_cast<const float4*>(&b1[hp * 16]);
    const float4* wp = reinterpret_cast<const float4*>(&W2[hp * 16]);
    float bb[16], ww[16];
#pragma unroll
    for (int i = 0; i < 4; ++i) {
        float4 b4 = bp[i], w4 = wp[i];
        bb[4 * i] = b4.x; bb[4 * i + 1] = b4.y; bb[4 * i + 2] = b4.z; bb[4 * i + 3] = b4.w;
        ww[4 * i] = w4.x; ww[4 * i + 1] = w4.y; ww[4 * i + 2] = w4.z; ww[4 * i + 3] = w4.w;
    }
    float p = 0.f;
#pragma unroll
    for (int k = 0; k < 16; ++k) {
        float inv = (k < 8) ? inv0 : inv1;
        float v = acc[k] * inv + bb[k];
        v = v > 0.f ? v : (__expf(v) - 1.f);  // ELU, fast path
        p = fmaf(v, ww[k], p);
    }
#pragma unroll
    for (int o = 1; o <= 2; o <<= 1) p += __shfl_xor(p, o, 64);
    if (sub == 0) h2[n] = p;
}

// ---------------- fused layer2: softmax + aggregate + bias + sigmoid ----------------
__global__ __launch_bounds__(256) void k_agg2(
    const int* __restrict__ csr, const int* __restrict__ off, const int* __restrict__ deg,
    const float* __restrict__ h2,
    const float* __restrict__ ats2, const float* __restrict__ atd2,
    const float* __restrict__ b2, float* __restrict__ out, int N)
{
    int idx = blockIdx.x * 256 + threadIdx.x;
    int n = idx >> 4;
    int l16 = threadIdx.x & 15;
    if (n >= N) return;
    int beg = off[n];
    int end = beg + deg[n];
    float a_s = ats2[0], a_d = atd2[0];
    float adv = h2[n] * a_d;
    float den = 0.f, num = 0.f;
    for (int j = beg + l16; j < end; j += 16) {
        float hs = h2[csr[j]];
        float t = fmaf(hs, a_s, adv);
        t = fmaxf(t, 0.2f * t);
        float ex = __expf(t);
        den += ex;
        num = fmaf(ex, hs, num);
    }
#pragma unroll
    for (int o = 1; o <= 8; o <<= 1) {
        den += __shfl_xor(den, o, 64);
        num += __shfl_xor(num, o, 64);
    }
    if (l16 == 0) {
        float t = num / (den + 1e-16f) + b2[0];
        out[n] = 1.f / (1.f + __expf(-t));
    }
}

extern "C" void kernel_launch(void* const* d_in, const int* in_sizes, int n_in,
                              void* d_out, int out_size, void* d_ws, size_t ws_size,
                              hipStream_t stream)
{
    const float* x    = (const float*)d_in[0];
    const int*   ei   = (const int*)d_in[1];
    const float* W1   = (const float*)d_in[2];
    const float* ats1 = (const float*)d_in[3];
    const float* atd1 = (const float*)d_in[4];
    const float* b1   = (const float*)d_in[5];
    const float* W2   = (const float*)d_in[6];
    const float* ats2 = (const float*)d_in[7];
    const float* atd2 = (const float*)d_in[8];
    const float* b2   = (const float*)d_in[9];
    float* out = (float*)d_out;

    const int N = out_size;            // 100000
    const int E = in_sizes[1] / 2;     // 3200000
    const int Etot = E + N;
    const int NBUK = (N + 255) >> 8;   // 391 (<= MAXBUK)
    const size_t capElems = (size_t)NBUK << CAPLOG;   // 6.4M slots (25.6 MB)

    // workspace layout: ebuf | feature block | ints | Wt  (no union: fatA
    // writes ebuf concurrently with gemm1-half writing h1b/as1b/ad1)
    char* base = (char*)d_ws;
    uint_t* ebuf = (uint_t*)base;
    size_t ebufBytes = (capElems * sizeof(uint_t) + 255) & ~(size_t)255;
    ushort_t* h1b  = (ushort_t*)(base + ebufBytes);
    ushort_t* as1b = h1b + (size_t)N * C1;
    float* ad1 = (float*)(as1b + (size_t)N * NH);
    float* h2  = ad1 + (size_t)N * NH;
    char* pend = (char*)(h2 + N);
    size_t featEnd = ((size_t)(pend - base) + 255) & ~(size_t)255;
    int* deg     = (int*)(base + featEnd);
    int* off     = deg + N;
    int* bkt_cnt = off + N;
    int* csr     = bkt_cnt + MAXBUK;
    ushort_t* wtg = (ushort_t*)(csr + capElems);   // 32 KB global Wt

    const int nbsc = (Etot + SC_CHUNK - 1) / SC_CHUNK;     // 403
    const int halfNodes = (((N / 2) + 127) / 128) * 128;   // 50048
    const int ga = halfNodes / 128;                        // 391 gemm blocks (first half)
    const int gb = (N - halfNodes + 127) / 128;            // 391 gemm blocks (second half)

    k_prep<<<64, 256, 0, stream>>>(W1, wtg, bkt_cnt);
    k_fatA<<<nbsc + ga, 512, 0, stream>>>(ei, E, N, NBUK, bkt_cnt, ebuf,
                                          x, wtg, ats1, atd1, h1b, as1b, ad1, nbsc);
    k_fatB<<<NBUK + gb, 512, 0, stream>>>(ebuf, bkt_cnt, N, deg, off, csr,
                                          x, wtg, ats1, atd1, h1b, as1b, ad1,
                                          NBUK, halfNodes);
    k_agg1<<<(N * 16 + 255) / 256, 256, 0, stream>>>(csr, off, deg, as1b, ad1, h1b, b1, W2, h2, N);
    k_agg2<<<(N * 16 + 255) / 256, 256, 0, stream>>>(csr, off, deg, h2, ats2, atd2, b2, out, N);
}